// Round 7
// baseline (232.374 us; speedup 1.0000x reference)
//
#include <hip/hip_runtime.h>
#include <stdint.h>

typedef unsigned short u16;
typedef u16   u16x4    __attribute__((ext_vector_type(4)));
typedef u16   u16x8    __attribute__((ext_vector_type(8)));
typedef u16x8 u16x8_ma __attribute__((may_alias));
typedef __bf16 bf16x8  __attribute__((ext_vector_type(8)));
typedef float f32x4    __attribute__((ext_vector_type(4)));
typedef f32x4 f32x4_ma __attribute__((may_alias));

#define EMB    1024
#define NHEAD  16
#define HD     64
#define SEQ    2048
#define NBATCH 2
#define ROWS   (NBATCH*SEQ)   // 4096
#define TSTRIDE 132           // producer V-transpose LDS stride

__device__ __forceinline__ u16 f2b(float f) {
  uint32_t u; __builtin_memcpy(&u, &f, 4);
  u = u + 0x7fffu + ((u >> 16) & 1u);
  return (u16)(u >> 16);
}
__device__ __forceinline__ u16x8 ld8(const u16* p) { return *(const u16x8_ma*)p; }
__device__ __forceinline__ void  st8(u16* p, u16x8 v) { *(u16x8_ma*)p = v; }
__device__ __forceinline__ bf16x8 asbf(u16x8 v) {
  union { u16x8 u; bf16x8 b; } c; c.u = v; return c.b;
}
// packed f32x2 -> bf16x2 (RNE), T12 recipe (no builtin on gfx950)
__device__ __forceinline__ uint32_t cvtpk(float a, float b) {
  uint32_t r;
  asm("v_cvt_pk_bf16_f32 %0, %1, %2" : "=v"(r) : "v"(a), "v"(b));
  return r;
}
// async global->LDS, 16B/lane; LDS dest = wave-uniform base + lane*16 (m97).
__device__ __forceinline__ void async_cp16(const u16* g, u16* l) {
  __builtin_amdgcn_global_load_lds(
      (const __attribute__((address_space(1))) void*)g,
      (__attribute__((address_space(3))) void*)l, 16, 0, 0);
}
// XCD-chunked bijective block swizzle (T1).
__device__ __forceinline__ void xcd_swz(int gx, int gy, int &bx, int &by) {
  int lin = bx + gx * by;
  int q = (gx * gy) >> 3;
  int w = (lin & 7) * q + (lin >> 3);
  bx = w % gx; by = w / gx;
}
// attn LDS tile: [64][64] u16 with XOR swizzle (bank-balanced, 8 lanes per
// 4-bank group on all access patterns; applied on BOTH write and read).
__device__ __forceinline__ int swz(int row, int col) {
  return row * 64 + (col ^ ((row & 7) << 3));
}

// ---------------------------------------------------------------------------
// Fused f32 -> bf16 conversion: x (4096 blocks) + 4 weights (1024 each).
// ---------------------------------------------------------------------------
__global__ __launch_bounds__(256) void cvt_all(
    const float* __restrict__ x,
    const float* __restrict__ w0, const float* __restrict__ w1,
    const float* __restrict__ w2, const float* __restrict__ w3,
    u16* __restrict__ xd, u16* __restrict__ d0, u16* __restrict__ d1,
    u16* __restrict__ d2, u16* __restrict__ d3)
{
  int bid = blockIdx.x;
  const float* s; u16* d; int off;
  if (bid < 4096) { s = x; d = xd; off = bid; }
  else {
    int t = bid - 4096; int m = t >> 10; off = t & 1023;
    switch (m) {
      case 0: s = w0; d = d0; break;
      case 1: s = w1; d = d1; break;
      case 2: s = w2; d = d2; break;
      default: s = w3; d = d3; break;
    }
  }
  size_t i = ((size_t)off * 256 + threadIdx.x) * 4;
  f32x4 v = *(const f32x4_ma*)(s + i);
  u16x4 o;
  #pragma unroll
  for (int j = 0; j < 4; j++) o[j] = f2b(v[j]);
  *(u16x4*)(d + i) = o;
}

// ---------------------------------------------------------------------------
// 128x128 GEMM core, BK=64 via dual 128x32 panels (m97 layout preserved).
// ---------------------------------------------------------------------------
template<int AMODE>
__device__ __forceinline__ void gemm_acc_128x128(
    const u16* __restrict__ A, const u16* __restrict__ B,
    int m0, int n0, u16* As, u16* Bs, f32x4 acc[4][4])
{
  const int tid  = threadIdx.x;
  const int lane = tid & 63;
  const int wave = tid >> 6;
  const int wm   = (wave >> 1) * 64;
  const int wn   = (wave & 1) * 64;
  const int ar   = tid >> 2;        // 0..63
  const int ac   = (tid & 3) * 8;   // 0,8,16,24
  const int lm   = lane & 15;
  const int lk   = (lane >> 4) * 8;

  #pragma unroll
  for (int i = 0; i < 4; i++)
    #pragma unroll
    for (int j = 0; j < 4; j++)
      #pragma unroll
      for (int e = 0; e < 4; e++) acc[i][j][e] = 0.f;

  for (int k0 = 0; k0 < EMB; k0 += 64) {
    size_t a0[2], a1[2];
    #pragma unroll
    for (int pnl = 0; pnl < 2; pnl++) {
      int kc = k0 + pnl * 32 + ac;
      if (AMODE == 0) {
        a0[pnl] = (size_t)(m0 + ar)      * EMB + kc;
        a1[pnl] = (size_t)(m0 + ar + 64) * EMB + kc;
      } else {
        int h = kc >> 6, d = kc & 63;
        int r0 = m0 + ar, r1 = m0 + ar + 64;
        a0[pnl] = (((size_t)((r0 >> 11) * NHEAD + h)) * SEQ + (r0 & (SEQ-1))) * HD + d;
        a1[pnl] = (((size_t)((r1 >> 11) * NHEAD + h)) * SEQ + (r1 & (SEQ-1))) * HD + d;
      }
    }
    __syncthreads();   // previous iteration's LDS reads complete
    #pragma unroll
    for (int pnl = 0; pnl < 2; pnl++) {
      const int pb = pnl * 4096;   // panel base (elems)
      async_cp16(A + a0[pnl], As + pb + tid * 8);
      async_cp16(A + a1[pnl], As + pb + (tid + 256) * 8);
      async_cp16(B + (size_t)(n0 + ar)      * EMB + k0 + pnl * 32 + ac, Bs + pb + tid * 8);
      async_cp16(B + (size_t)(n0 + ar + 64) * EMB + k0 + pnl * 32 + ac, Bs + pb + (tid + 256) * 8);
    }
    __syncthreads();   // drains vmcnt: both panels ready

    #pragma unroll
    for (int pnl = 0; pnl < 2; pnl++) {
      const int pb = pnl * 4096;
      bf16x8 af[4], bfr[4];
      #pragma unroll
      for (int i = 0; i < 4; i++)
        af[i] = asbf(ld8(As + pb + (wm + i * 16 + lm) * 32 + lk));
      #pragma unroll
      for (int j = 0; j < 4; j++)
        bfr[j] = asbf(ld8(Bs + pb + (wn + j * 16 + lm) * 32 + lk));
      #pragma unroll
      for (int i = 0; i < 4; i++)
        #pragma unroll
        for (int j = 0; j < 4; j++)
          acc[i][j] = __builtin_amdgcn_mfma_f32_16x16x32_bf16(af[i], bfr[j], acc[i][j], 0, 0, 0);
    }
  }
}

// LN over the wave's 64-col head span + scatter to bf16 [N, Hdst, L, 64].
__device__ __forceinline__ void epilogue_scatter_ln(
    f32x4 acc[4][4], u16* dst, int m0, int n0, int head_base, int Hdst,
    const float* g, const float* b, int do_ln)
{
  const int lane = threadIdx.x & 63, wave = threadIdx.x >> 6;
  const int wm = (wave >> 1) * 64, wn = (wave & 1) * 64;
  const int lm = lane & 15, quad = lane >> 4;

  float gv[4], bv[4];
  #pragma unroll
  for (int j = 0; j < 4; j++) { gv[j] = g[j * 16 + lm]; bv[j] = b[j * 16 + lm]; }

  #pragma unroll
  for (int i = 0; i < 4; i++)
    #pragma unroll
    for (int r = 0; r < 4; r++) {
      float val[4];
      #pragma unroll
      for (int j = 0; j < 4; j++) val[j] = acc[i][j][r];
      if (do_ln) {
        float s = val[0] + val[1] + val[2] + val[3];
        #pragma unroll
        for (int o = 8; o >= 1; o >>= 1) s += __shfl_xor(s, o, 64);
        float mean = s * (1.f / 64.f);
        float ss = 0.f;
        #pragma unroll
        for (int j = 0; j < 4; j++) { val[j] -= mean; ss += val[j] * val[j]; }
        #pragma unroll
        for (int o = 8; o >= 1; o >>= 1) ss += __shfl_xor(ss, o, 64);
        float inv = rsqrtf(ss * (1.f / 64.f) + 1e-5f);
        #pragma unroll
        for (int j = 0; j < 4; j++) val[j] = val[j] * inv * gv[j] + bv[j];
      }
      int row = m0 + wm + i * 16 + quad * 4 + r;
      int bn = row >> 11, l = row & (SEQ - 1);
      #pragma unroll
      for (int j = 0; j < 4; j++) {
        int col = n0 + wn + j * 16 + lm;
        int hl = (col >> 6) - head_base, d = col & 63;
        dst[(((size_t)(bn * Hdst + hl)) * SEQ + l) * HD + d] = f2b(val[j]);
      }
    }
}

// V epilogue: transpose the 128x128 tile through LDS (Ts reuses dead As/Bs),
// then write V^T ([N, Hdst, 64, SEQ]) with fully coalesced 16B stores.
__device__ __forceinline__ void epilogue_transpose_v(
    f32x4 acc[4][4], u16* dst, int m0, int n0, int Hdst, u16* Ts)
{
  const int tid = threadIdx.x, lane = tid & 63, wave = tid >> 6;
  const int wm = (wave >> 1) * 64;
  const int lm = lane & 15, quad = lane >> 4;
  const int bn = m0 >> 11, l0 = m0 & (SEQ - 1);

  #pragma unroll
  for (int pass = 0; pass < 2; ++pass) {
    __syncthreads();   // Ts region free (main-loop / previous-pass reads done)
    if ((wave & 1) == pass) {
      #pragma unroll
      for (int i = 0; i < 4; i++)
        #pragma unroll
        for (int j = 0; j < 4; j++)
          #pragma unroll
          for (int r = 0; r < 4; r++)
            Ts[(j * 16 + lm) * TSTRIDE + wm + i * 16 + quad * 4 + r] =
                f2b(acc[i][j][r]);
    }
    __syncthreads();
    const int hl = (n0 >> 6) + pass;
    u16* base = dst + ((size_t)(bn * Hdst + hl)) * HD * SEQ + l0;
    #pragma unroll
    for (int it = 0; it < 4; ++it) {
      int e = it * 2048 + tid * 8;
      int d = e >> 7, l = e & 127;
      st8(base + (size_t)d * SEQ + l, ld8(Ts + d * TSTRIDE + l));
    }
  }
}

// Q/K projection: grid (8, 32, 2), XCD-swizzled.
__global__ __launch_bounds__(256) void gemm_qk(
    const u16* __restrict__ x,
    const u16* __restrict__ Wq, const u16* __restrict__ Wk,
    const float* __restrict__ gq, const float* __restrict__ bq,
    const float* __restrict__ gk, const float* __restrict__ bk,
    u16* __restrict__ qd, u16* __restrict__ kb)
{
  __shared__ __align__(16) u16 As[128 * 64];
  __shared__ __align__(16) u16 Bs[128 * 64];
  int bx = blockIdx.x, by = blockIdx.y;
  xcd_swz(8, 32, bx, by);
  const int m0 = by * 128, n0 = bx * 128;
  f32x4 acc[4][4];
  if (blockIdx.z == 0) {
    gemm_acc_128x128<0>(x, Wq, m0, n0, As, Bs, acc);
    epilogue_scatter_ln(acc, qd, m0, n0, 0, NHEAD, gq, bq, 1);
  } else {
    gemm_acc_128x128<0>(x, Wk, m0, n0, As, Bs, acc);
    epilogue_scatter_ln(acc, kb, m0, n0, 0, NHEAD, gk, bk, 1);
  }
}

// V projection (transposed output): grid (8, 32), XCD-swizzled.
__global__ __launch_bounds__(256) void gemm_v(
    const u16* __restrict__ x, const u16* __restrict__ Wv,
    u16* __restrict__ vb)
{
  __shared__ __align__(16) u16 buf[128 * 64 * 2];  // As | Bs, reused as Ts
  u16* As = buf;
  u16* Bs = buf + 128 * 64;
  int bx = blockIdx.x, by = blockIdx.y;
  xcd_swz(8, 32, bx, by);
  const int m0 = by * 128, n0 = bx * 128;
  f32x4 acc[4][4];
  gemm_acc_128x128<0>(x, Wv, m0, n0, As, Bs, acc);
  epilogue_transpose_v(acc, vb, m0, n0, NHEAD, buf);
}

// Fallback kernels for small-workspace multi-pass K/V.
__global__ __launch_bounds__(256) void gemm_q(
    const u16* __restrict__ x, const u16* __restrict__ Wq,
    const float* __restrict__ gq, const float* __restrict__ bq,
    u16* __restrict__ qd)
{
  __shared__ __align__(16) u16 As[128 * 64];
  __shared__ __align__(16) u16 Bs[128 * 64];
  int bx = blockIdx.x, by = blockIdx.y;
  xcd_swz(8, 32, bx, by);
  const int m0 = by * 128, n0 = bx * 128;
  f32x4 acc[4][4];
  gemm_acc_128x128<0>(x, Wq, m0, n0, As, Bs, acc);
  epilogue_scatter_ln(acc, qd, m0, n0, 0, NHEAD, gq, bq, 1);
}
__global__ __launch_bounds__(256) void gemm_kv(
    const u16* __restrict__ x,
    const u16* __restrict__ Wk, const u16* __restrict__ Wv,
    const float* __restrict__ gk, const float* __restrict__ bk,
    u16* __restrict__ k, u16* __restrict__ v, int head_lo, int hpp)
{
  __shared__ __align__(16) u16 buf[128 * 64 * 2];
  u16* As = buf;
  u16* Bs = buf + 128 * 64;
  int bx = blockIdx.x, by = blockIdx.y;
  xcd_swz(hpp / 2, 32, bx, by);
  const int m0 = by * 128, n0 = bx * 128;
  const u16* W = (blockIdx.z == 0 ? Wk : Wv) + (size_t)head_lo * HD * EMB;
  f32x4 acc[4][4];
  gemm_acc_128x128<0>(x, W, m0, n0, As, Bs, acc);
  if (blockIdx.z == 0)
    epilogue_scatter_ln(acc, k, m0, n0, 0, hpp, gk, bk, 1);
  else
    epilogue_transpose_v(acc, v, m0, n0, hpp, buf);
}

// ---------------------------------------------------------------------------
// Flash causal attention — 2 waves/block, 2 Q-fragments per wave.
// grid (32, hpp, NBATCH), block 128. Complementary-pair tile map (R3).
//
// Each K/V fragment ds_read_b128 now feeds TWO MFMAs (frag A and frag B of
// the same wave): per-block-iter LDS cycles 1160 -> ~776 (the b128 fragment
// reads were the largest LDS-pipe term; LDS pipe was ~58% of attn R6).
// K/Vt tiles are XOR-swizzled [64][64] (col ^= (row&7)<<3, write AND read):
// same bank balance as the old SATT=72 but 32 KB total -> 5 blocks/CU cap.
// ---------------------------------------------------------------------------
__global__ __launch_bounds__(128, 3) void attn(
    u16* qd, const u16* __restrict__ K, const u16* __restrict__ V,
    int head_lo, int hpp)
{
  __shared__ __align__(16) u16 Ks[2][64 * 64];
  __shared__ __align__(16) u16 Vt[2][64 * 64];   // V^T: rows=d, cols=key

  const int hl = blockIdx.y, n = blockIdx.z;
  const int perm = (7 * blockIdx.x + (hl & 7) + 8 * n) & 31;
  const int p = perm ^ (31 * (hl >> 3));            // complementary pairs
  const int tid = threadIdx.x, lane = tid & 63, wave = tid >> 6;  // wave 0..1
  const int lm = lane & 15, quad = lane >> 4, lk = quad * 8;
  u16* Qh = qd + ((size_t)(n * NHEAD + head_lo + hl)) * SEQ * HD;
  const u16* Kh = K + ((size_t)(n * hpp + hl)) * SEQ * HD;
  const u16* Vh = V + ((size_t)(n * hpp + hl)) * HD * SEQ;   // transposed

  // staging: instruction j covers rows (tid>>3)+16j, cols (tid&7)*8..+7
  const int srow = tid >> 3;        // 0..15
  const int scol = (tid & 7) * 8;   // 0..56

  // Q fragments (B-operand of swapped QK^T): rows p*64 + wave*32 + {lm, 16+lm}
  bf16x8 aqA[2], aqB[2];
  #pragma unroll
  for (int ks = 0; ks < 2; ++ks) {
    aqA[ks] = asbf(ld8(Qh + (size_t)(p * 64 + wave * 32 + lm)      * HD + ks * 32 + lk));
    aqB[ks] = asbf(ld8(Qh + (size_t)(p * 64 + wave * 32 + 16 + lm) * HD + ks * 32 + lk));
  }

  u16x8 kr[4], vr[4];
  #pragma unroll
  for (int j = 0; j < 4; j++) {
    int r = srow + 16 * j;
    kr[j] = ld8(Kh + (size_t)r * HD + scol);
    vr[j] = ld8(Vh + (size_t)r * SEQ + scol);
    st8(&Ks[0][swz(r, scol)], kr[j]);
    st8(&Vt[0][swz(r, scol)], vr[j]);
  }
  #pragma unroll
  for (int j = 0; j < 4; j++) {
    int r = srow + 16 * j;
    kr[j] = ld8(Kh + (size_t)(64 + r) * HD + scol);
    vr[j] = ld8(Vh + (size_t)r * SEQ + 64 + scol);
  }
  __syncthreads();

  f32x4 oA[4], oB[4];
  #pragma unroll
  for (int j = 0; j < 4; j++)
    #pragma unroll
    for (int e = 0; e < 4; e++) { oA[j][e] = 0.f; oB[j][e] = 0.f; }
  float mA = -1e30f, mB = -1e30f, psA = 0.f, psB = 0.f;

  const int idx0 = (((quad & 1) * 2) * 16 + lm) * 4;   // bpermute byte idx, w<2
  const int idx1 = idx0 + 64;                          // w>=2
  const int qrowA = p * 64 + wave * 32 + lm;
  const int qrowB = qrowA + 16;

  for (int t = 0; t <= p; ++t) {
    const int cur = t & 1;
    if (t < p) {
      const int nb = 1 - cur;
      #pragma unroll
      for (int j = 0; j < 4; j++) {
        int r = srow + 16 * j;
        st8(&Ks[nb][swz(r, scol)], kr[j]);
        st8(&Vt[nb][swz(r, scol)], vr[j]);
      }
      if (t + 1 < p) {
        const size_t base = (size_t)(t + 2) * 64;
        #pragma unroll
        for (int j = 0; j < 4; j++) {
          int r = srow + 16 * j;
          kr[j] = ld8(Kh + (base + r) * HD + scol);
          vr[j] = ld8(Vh + (size_t)r * SEQ + base + scol);
        }
      }
    }

    // S^T for both fragments; each K-frag read feeds 2 MFMAs.
    f32x4 sA[4], sB[4];
    #pragma unroll
    for (int j = 0; j < 4; j++)
      #pragma unroll
      for (int e = 0; e < 4; e++) { sA[j][e] = 0.f; sB[j][e] = 0.f; }
    __builtin_amdgcn_s_setprio(1);
    #pragma unroll
    for (int ks = 0; ks < 2; ++ks)
      #pragma unroll
      for (int j = 0; j < 4; j++) {
        bf16x8 ak = asbf(ld8(&Ks[cur][swz(j * 16 + lm, ks * 32 + lk)]));
        sA[j] = __builtin_amdgcn_mfma_f32_16x16x32_bf16(ak, aqA[ks], sA[j], 0, 0, 0);
        sB[j] = __builtin_amdgcn_mfma_f32_16x16x32_bf16(ak, aqB[ks], sB[j], 0, 0, 0);
      }
    __builtin_amdgcn_s_setprio(0);

    if (t == p) {   // causal mask on the diagonal tile
      #pragma unroll
      for (int j = 0; j < 4; j++)
        #pragma unroll
        for (int r = 0; r < 4; r++) {
          int key = t * 64 + j * 16 + quad * 4 + r;
          if (key > qrowA) sA[j][r] = -1e30f;
          if (key > qrowB) sB[j][r] = -1e30f;
        }
    }

    uint32_t uA[8], uB[8];
    // ---- softmax fragment A (sA dies after uA) ----
    {
      float mx = fmaxf(fmaxf(sA[0][0], sA[0][1]), fmaxf(sA[0][2], sA[0][3]));
      #pragma unroll
      for (int j = 1; j < 4; j++)
        mx = fmaxf(mx, fmaxf(fmaxf(sA[j][0], sA[j][1]), fmaxf(sA[j][2], sA[j][3])));
      mx = fmaxf(mx, __shfl_xor(mx, 16, 64));
      mx = fmaxf(mx, __shfl_xor(mx, 32, 64));
      const float mnew = fmaxf(mA, mx);
      const float alpha = __expf(mA - mnew);
      mA = mnew;
      float part = 0.f;
      #pragma unroll
      for (int j = 0; j < 4; j++)
        #pragma unroll
        for (int r = 0; r < 4; r++) {
          float pv = __expf(sA[j][r] - mnew);
          sA[j][r] = pv;
          part += pv;
        }
      psA = psA * alpha + part;
      float ar_[4];
      #pragma unroll
      for (int r = 0; r < 4; r++)
        ar_[r] = __shfl(alpha, (lane & 48) | (quad * 4 + r), 64);
      #pragma unroll
      for (int j = 0; j < 4; j++)
        #pragma unroll
        for (int r = 0; r < 4; r++) oA[j][r] *= ar_[r];
      #pragma unroll
      for (int j = 0; j < 4; j++) {
        uA[2 * j]     = cvtpk(sA[j][0], sA[j][1]);
        uA[2 * j + 1] = cvtpk(sA[j][2], sA[j][3]);
      }
    }
    // ---- softmax fragment B ----
    {
      float mx = fmaxf(fmaxf(sB[0][0], sB[0][1]), fmaxf(sB[0][2], sB[0][3]));
      #pragma unroll
      for (int j = 1; j < 4; j++)
        mx = fmaxf(mx, fmaxf(fmaxf(sB[j][0], sB[j][1]), fmaxf(sB[j][2], sB[j][3])));
      mx = fmaxf(mx, __shfl_xor(mx, 16, 64));
      mx = fmaxf(mx, __shfl_xor(mx, 32, 64));
      const float mnew = fmaxf(mB, mx);
      const float alpha = __expf(mB - mnew);
      mB = mnew;
      float part = 0.f;
      #pragma unroll
      for (int j = 0; j < 4; j++)
        #pragma unroll
        for (int r = 0; r < 4; r++) {
          float pv = __expf(sB[j][r] - mnew);
          sB[j][r] = pv;
          part += pv;
        }
      psB = psB * alpha + part;
      float ar_[4];
      #pragma unroll
      for (int r = 0; r < 4; r++)
        ar_[r] = __shfl(alpha, (lane & 48) | (quad * 4 + r), 64);
      #pragma unroll
      for (int j = 0; j < 4; j++)
        #pragma unroll
        for (int r = 0; r < 4; r++) oB[j][r] *= ar_[r];
      #pragma unroll
      for (int j = 0; j < 4; j++) {
        uB[2 * j]     = cvtpk(sB[j][0], sB[j][1]);
        uB[2 * j + 1] = cvtpk(sB[j][2], sB[j][3]);
      }
    }

    // PV: each V-frag read feeds 2 MFMAs.
    __builtin_amdgcn_s_setprio(1);
    #pragma unroll
    for (int ks = 0; ks < 2; ++ks) {
      union { uint32_t w[4]; bf16x8 v; } cA, cB;
      #pragma unroll
      for (int w = 0; w < 4; w++) {
        int idx = w < 2 ? idx0 : idx1;
        int loA = __builtin_amdgcn_ds_bpermute(idx, (int)uA[ks * 4 + (w & 1)]);
        int hiA = __builtin_amdgcn_ds_bpermute(idx, (int)uA[ks * 4 + 2 + (w & 1)]);
        cA.w[w] = (quad < 2) ? (uint32_t)loA : (uint32_t)hiA;
        int loB = __builtin_amdgcn_ds_bpermute(idx, (int)uB[ks * 4 + (w & 1)]);
        int hiB = __builtin_amdgcn_ds_bpermute(idx, (int)uB[ks * 4 + 2 + (w & 1)]);
        cB.w[w] = (quad < 2) ? (uint32_t)loB : (uint32_t)hiB;
      }
      #pragma unroll
      for (int j = 0; j < 4; j++) {
        bf16x8 bv = asbf(ld8(&Vt[cur][swz(j * 16 + lm, ks * 32 + lk)]));
        oA[j] = __builtin_amdgcn_mfma_f32_16x16x32_bf16(cA.v, bv, oA[j], 0, 0, 0);
        oB[j] = __builtin_amdgcn_mfma_f32_16x16x32_bf16(cB.v, bv, oB[j], 0, 0, 0);
      }
    }
    __builtin_amdgcn_s_setprio(0);
    __syncthreads();   // single per-iteration barrier (dbuf swap)
  }

  // epilogue: row sums live at row lm; gather inv to O rows quad*4+r
  float sa = psA, sb = psB;
  sa += __shfl_xor(sa, 16, 64); sa += __shfl_xor(sa, 32, 64);
  sb += __shfl_xor(sb, 16, 64); sb += __shfl_xor(sb, 32, 64);
  const float invA = 1.0f / sa, invB = 1.0f / sb;
  #pragma unroll
  for (int r = 0; r < 4; r++) {
    float iA = __shfl(invA, (lane & 48) | (quad * 4 + r), 64);
    float iB = __shfl(invB, (lane & 48) | (quad * 4 + r), 64);
    const int rowA = p * 64 + wave * 32 + quad * 4 + r;
    const int rowB = rowA + 16;
    #pragma unroll
    for (int j = 0; j < 4; j++) {
      Qh[(size_t)rowA * HD + j * 16 + lm] = f2b(oA[j][r] * iA);
      Qh[(size_t)rowB * HD + j * 16 + lm] = f2b(oB[j][r] * iB);
    }
  }
}

// ---------------------------------------------------------------------------
// Output projection, 64x128 tiles, BK=64 dual-panel: grid (8, 64),
// XCD-swizzled. d_out(f32) = ao @ Wo^T + bo ; ao in [N,16,L,64] bf16.
// ---------------------------------------------------------------------------
__global__ __launch_bounds__(256) void gemm_out(
    const u16* __restrict__ ao, const u16* __restrict__ Wo,
    const float* __restrict__ bo, float* __restrict__ out)
{
  __shared__ __align__(16) u16 As[64 * 64];    // 2 panels of 64x32
  __shared__ __align__(16) u16 Bs[128 * 64];   // 2 panels of 128x32
  int bx = blockIdx.x, by = blockIdx.y;
  xcd_swz(8, 64, bx, by);
  const int m0 = by * 64, n0 = bx * 128;
  const int tid  = threadIdx.x;
  const int lane = tid & 63;
  const int wave = tid >> 6;
  const int wm   = (wave >> 1) * 32;
  const int wn   = (wave & 1) * 64;
  const int ar   = tid >> 2;        // 0..63
  const int ac   = (tid & 3) * 8;
  const int lm   = lane & 15;
  const int lk   = (lane >> 4) * 8;

  f32x4 acc[2][4];
  #pragma unroll
  for (int i = 0; i < 2; i++)
    #pragma unroll
    for (int j = 0; j < 4; j++)
      #pragma unroll
      for (int e = 0; e < 4; e++) acc[i][j][e] = 0.f;

  for (int k0 = 0; k0 < EMB; k0 += 64) {
    size_t aoff[2];
    #pragma unroll
    for (int pnl = 0; pnl < 2; pnl++) {
      int kc = k0 + pnl * 32 + ac, h = kc >> 6, d = kc & 63;
      int r0 = m0 + ar;
      aoff[pnl] = (((size_t)((r0 >> 11) * NHEAD + h)) * SEQ + (r0 & (SEQ-1))) * HD + d;
    }
    __syncthreads();
    #pragma unroll
    for (int pnl = 0; pnl < 2; pnl++) {
      async_cp16(ao + aoff[pnl], As + pnl * 2048 + tid * 8);
      async_cp16(Wo + (size_t)(n0 + ar)      * EMB + k0 + pnl * 32 + ac, Bs + pnl * 4096 + tid * 8);
      async_cp16(Wo + (size_t)(n0 + ar + 64) * EMB + k0 + pnl * 32 + ac, Bs + pnl * 4096 + (tid + 256) * 8);
    }
    __syncthreads();

    #pragma unroll
    for (int pnl = 0; pnl < 2; pnl++) {
      bf16x8 af[2], bfr[4];
      #pragma unroll
      for (int i = 0; i < 2; i++)
        af[i] = asbf(ld8(As + pnl * 2048 + (wm + i * 16 + lm) * 32 + lk));
      #pragma unroll
      for (int j = 0; j < 4; j++)
        bfr[j] = asbf(ld8(Bs + pnl * 4096 + (wn + j * 16 + lm) * 32 + lk));
      #pragma unroll
      for (int i = 0; i < 2; i++)
        #pragma unroll
        for (int j = 0; j < 4; j++)
          acc[i][j] = __builtin_amdgcn_mfma_f32_16x16x32_bf16(af[i], bfr[j], acc[i][j], 0, 0, 0);
    }
  }

  const int quad = lane >> 4;
  #pragma unroll
  for (int j = 0; j < 4; j++) {
    int col = n0 + wn + j * 16 + lm;
    float bias = bo[col];
    #pragma unroll
    for (int i = 0; i < 2; i++)
      #pragma unroll
      for (int r = 0; r < 4; r++) {
        int row = m0 + wm + i * 16 + quad * 4 + r;
        out[(size_t)row * EMB + col] = acc[i][j][r] + bias;
      }
  }
}

extern "C" void kernel_launch(void* const* d_in, const int* in_sizes, int n_in,
                              void* d_out, int out_size, void* d_ws, size_t ws_size,
                              hipStream_t stream)
{
  const float* xf  = (const float*)d_in[0];
  const float* Wqf = (const float*)d_in[2];
  const float* Wkf = (const float*)d_in[3];
  const float* Wvf = (const float*)d_in[4];
  const float* gq  = (const float*)d_in[5];
  const float* bq  = (const float*)d_in[6];
  const float* gk  = (const float*)d_in[7];
  const float* bk  = (const float*)d_in[8];
  const float* Wof = (const float*)d_in[9];
  const float* bo  = (const float*)d_in[10];

  const size_t MB = 1u << 20;
  u16* xb  = (u16*)d_ws;                           // 8 MiB
  u16* wqb = xb  + (size_t)ROWS * EMB;             // 2 MiB each
  u16* wkb = wqb + (size_t)EMB * EMB;
  u16* wvb = wkb + (size_t)EMB * EMB;
  u16* wob = wvb + (size_t)EMB * EMB;
  u16* kvbase = wob + (size_t)EMB * EMB;           // ws + 16 MiB

  size_t avail = (ws_size > 16 * MB) ? ws_size - 16 * MB : 2 * MB;
  int hpp = NHEAD;
  while ((size_t)hpp * MB > avail && hpp > 2) hpp >>= 1;
  const size_t kv_elems = (size_t)hpp * NBATCH * SEQ * HD;
  u16* kbuf = kvbase;
  u16* vbuf = kbuf + kv_elems;

  // Q (bf16, + in-place attn output) lives in the x input buffer (dead
  // after cvt_all). gemm_out writes f32 straight to d_out.
  u16* qd = (u16*)d_in[0];
  float* out = (float*)d_out;

  cvt_all<<<dim3(8192), 256, 0, stream>>>(xf, Wqf, Wkf, Wvf, Wof,
                                          xb, wqb, wkb, wvb, wob);
  if (hpp == NHEAD) {
    gemm_qk<<<dim3(8, 32, 2), 256, 0, stream>>>(xb, wqb, wkb,
                                                gq, bq, gk, bk, qd, kbuf);
    gemm_v<<<dim3(8, 32), 256, 0, stream>>>(xb, wvb, vbuf);
    attn<<<dim3(32, NHEAD, NBATCH), 128, 0, stream>>>(qd, kbuf, vbuf, 0, NHEAD);
  } else {
    gemm_q<<<dim3(8, 32), 256, 0, stream>>>(xb, wqb, gq, bq, qd);
    for (int g = 0; g < NHEAD / hpp; ++g) {
      gemm_kv<<<dim3(hpp / 2, 32, 2), 256, 0, stream>>>(xb, wkb, wvb, gk, bk,
                                                        kbuf, vbuf, g * hpp, hpp);
      attn<<<dim3(32, hpp, NBATCH), 128, 0, stream>>>(qd, kbuf, vbuf, g * hpp, hpp);
    }
  }
  gemm_out<<<dim3(8, 64), 256, 0, stream>>>(qd, wob, bo, out);
}

// Round 8
// 222.189 us; speedup vs baseline: 1.0458x; 1.0458x over previous
//
#include <hip/hip_runtime.h>
#include <stdint.h>

typedef unsigned short u16;
typedef u16   u16x4    __attribute__((ext_vector_type(4)));
typedef u16   u16x8    __attribute__((ext_vector_type(8)));
typedef u16x8 u16x8_ma __attribute__((may_alias));
typedef __bf16 bf16x8  __attribute__((ext_vector_type(8)));
typedef float f32x4    __attribute__((ext_vector_type(4)));
typedef f32x4 f32x4_ma __attribute__((may_alias));

#define EMB    1024
#define NHEAD  16
#define HD     64
#define SEQ    2048
#define NBATCH 2
#define ROWS   (NBATCH*SEQ)   // 4096
#define SATT   72             // attn K/V^T LDS row stride (balanced 8x4-bank groups)
#define TSTRIDE 132           // producer V-transpose LDS stride

__device__ __forceinline__ u16 f2b(float f) {
  uint32_t u; __builtin_memcpy(&u, &f, 4);
  u = u + 0x7fffu + ((u >> 16) & 1u);
  return (u16)(u >> 16);
}
__device__ __forceinline__ u16x8 ld8(const u16* p) { return *(const u16x8_ma*)p; }
__device__ __forceinline__ void  st8(u16* p, u16x8 v) { *(u16x8_ma*)p = v; }
__device__ __forceinline__ bf16x8 asbf(u16x8 v) {
  union { u16x8 u; bf16x8 b; } c; c.u = v; return c.b;
}
// packed f32x2 -> bf16x2 (RNE), T12 recipe (no builtin on gfx950)
__device__ __forceinline__ uint32_t cvtpk(float a, float b) {
  uint32_t r;
  asm("v_cvt_pk_bf16_f32 %0, %1, %2" : "=v"(r) : "v"(a), "v"(b));
  return r;
}
// async global->LDS, 16B/lane; LDS dest = wave-uniform base + lane*16 (m97).
__device__ __forceinline__ void async_cp16(const u16* g, u16* l) {
  __builtin_amdgcn_global_load_lds(
      (const __attribute__((address_space(1))) void*)g,
      (__attribute__((address_space(3))) void*)l, 16, 0, 0);
}
// XCD-chunked bijective block swizzle (T1).
__device__ __forceinline__ void xcd_swz(int gx, int gy, int &bx, int &by) {
  int lin = bx + gx * by;
  int q = (gx * gy) >> 3;
  int w = (lin & 7) * q + (lin >> 3);
  bx = w % gx; by = w / gx;
}

// ---------------------------------------------------------------------------
// Fused f32 -> bf16 conversion: x (4096 blocks) + 4 weights (1024 each).
// ---------------------------------------------------------------------------
__global__ __launch_bounds__(256) void cvt_all(
    const float* __restrict__ x,
    const float* __restrict__ w0, const float* __restrict__ w1,
    const float* __restrict__ w2, const float* __restrict__ w3,
    u16* __restrict__ xd, u16* __restrict__ d0, u16* __restrict__ d1,
    u16* __restrict__ d2, u16* __restrict__ d3)
{
  int bid = blockIdx.x;
  const float* s; u16* d; int off;
  if (bid < 4096) { s = x; d = xd; off = bid; }
  else {
    int t = bid - 4096; int m = t >> 10; off = t & 1023;
    switch (m) {
      case 0: s = w0; d = d0; break;
      case 1: s = w1; d = d1; break;
      case 2: s = w2; d = d2; break;
      default: s = w3; d = d3; break;
    }
  }
  size_t i = ((size_t)off * 256 + threadIdx.x) * 4;
  f32x4 v = *(const f32x4_ma*)(s + i);
  u16x4 o;
  #pragma unroll
  for (int j = 0; j < 4; j++) o[j] = f2b(v[j]);
  *(u16x4*)(d + i) = o;
}

// ---------------------------------------------------------------------------
// 128x128 GEMM core, BK=64 via dual 128x32 panels (m97 layout preserved).
// ---------------------------------------------------------------------------
template<int AMODE>
__device__ __forceinline__ void gemm_acc_128x128(
    const u16* __restrict__ A, const u16* __restrict__ B,
    int m0, int n0, u16* As, u16* Bs, f32x4 acc[4][4])
{
  const int tid  = threadIdx.x;
  const int lane = tid & 63;
  const int wave = tid >> 6;
  const int wm   = (wave >> 1) * 64;
  const int wn   = (wave & 1) * 64;
  const int ar   = tid >> 2;        // 0..63
  const int ac   = (tid & 3) * 8;   // 0,8,16,24
  const int lm   = lane & 15;
  const int lk   = (lane >> 4) * 8;

  #pragma unroll
  for (int i = 0; i < 4; i++)
    #pragma unroll
    for (int j = 0; j < 4; j++)
      #pragma unroll
      for (int e = 0; e < 4; e++) acc[i][j][e] = 0.f;

  for (int k0 = 0; k0 < EMB; k0 += 64) {
    size_t a0[2], a1[2];
    #pragma unroll
    for (int pnl = 0; pnl < 2; pnl++) {
      int kc = k0 + pnl * 32 + ac;
      if (AMODE == 0) {
        a0[pnl] = (size_t)(m0 + ar)      * EMB + kc;
        a1[pnl] = (size_t)(m0 + ar + 64) * EMB + kc;
      } else {
        int h = kc >> 6, d = kc & 63;
        int r0 = m0 + ar, r1 = m0 + ar + 64;
        a0[pnl] = (((size_t)((r0 >> 11) * NHEAD + h)) * SEQ + (r0 & (SEQ-1))) * HD + d;
        a1[pnl] = (((size_t)((r1 >> 11) * NHEAD + h)) * SEQ + (r1 & (SEQ-1))) * HD + d;
      }
    }
    __syncthreads();   // previous iteration's LDS reads complete
    #pragma unroll
    for (int pnl = 0; pnl < 2; pnl++) {
      const int pb = pnl * 4096;   // panel base (elems)
      async_cp16(A + a0[pnl], As + pb + tid * 8);
      async_cp16(A + a1[pnl], As + pb + (tid + 256) * 8);
      async_cp16(B + (size_t)(n0 + ar)      * EMB + k0 + pnl * 32 + ac, Bs + pb + tid * 8);
      async_cp16(B + (size_t)(n0 + ar + 64) * EMB + k0 + pnl * 32 + ac, Bs + pb + (tid + 256) * 8);
    }
    __syncthreads();   // drains vmcnt: both panels ready

    #pragma unroll
    for (int pnl = 0; pnl < 2; pnl++) {
      const int pb = pnl * 4096;
      bf16x8 af[4], bfr[4];
      #pragma unroll
      for (int i = 0; i < 4; i++)
        af[i] = asbf(ld8(As + pb + (wm + i * 16 + lm) * 32 + lk));
      #pragma unroll
      for (int j = 0; j < 4; j++)
        bfr[j] = asbf(ld8(Bs + pb + (wn + j * 16 + lm) * 32 + lk));
      #pragma unroll
      for (int i = 0; i < 4; i++)
        #pragma unroll
        for (int j = 0; j < 4; j++)
          acc[i][j] = __builtin_amdgcn_mfma_f32_16x16x32_bf16(af[i], bfr[j], acc[i][j], 0, 0, 0);
    }
  }
}

// LN over the wave's 64-col head span + scatter to bf16 [N, Hdst, L, 64].
__device__ __forceinline__ void epilogue_scatter_ln(
    f32x4 acc[4][4], u16* dst, int m0, int n0, int head_base, int Hdst,
    const float* g, const float* b, int do_ln)
{
  const int lane = threadIdx.x & 63, wave = threadIdx.x >> 6;
  const int wm = (wave >> 1) * 64, wn = (wave & 1) * 64;
  const int lm = lane & 15, quad = lane >> 4;

  float gv[4], bv[4];
  #pragma unroll
  for (int j = 0; j < 4; j++) { gv[j] = g[j * 16 + lm]; bv[j] = b[j * 16 + lm]; }

  #pragma unroll
  for (int i = 0; i < 4; i++)
    #pragma unroll
    for (int r = 0; r < 4; r++) {
      float val[4];
      #pragma unroll
      for (int j = 0; j < 4; j++) val[j] = acc[i][j][r];
      if (do_ln) {
        float s = val[0] + val[1] + val[2] + val[3];
        #pragma unroll
        for (int o = 8; o >= 1; o >>= 1) s += __shfl_xor(s, o, 64);
        float mean = s * (1.f / 64.f);
        float ss = 0.f;
        #pragma unroll
        for (int j = 0; j < 4; j++) { val[j] -= mean; ss += val[j] * val[j]; }
        #pragma unroll
        for (int o = 8; o >= 1; o >>= 1) ss += __shfl_xor(ss, o, 64);
        float inv = rsqrtf(ss * (1.f / 64.f) + 1e-5f);
        #pragma unroll
        for (int j = 0; j < 4; j++) val[j] = val[j] * inv * gv[j] + bv[j];
      }
      int row = m0 + wm + i * 16 + quad * 4 + r;
      int bn = row >> 11, l = row & (SEQ - 1);
      #pragma unroll
      for (int j = 0; j < 4; j++) {
        int col = n0 + wn + j * 16 + lm;
        int hl = (col >> 6) - head_base, d = col & 63;
        dst[(((size_t)(bn * Hdst + hl)) * SEQ + l) * HD + d] = f2b(val[j]);
      }
    }
}

// V epilogue: transpose the 128x128 tile through LDS (Ts reuses dead As/Bs),
// then write V^T ([N, Hdst, 64, SEQ]) with fully coalesced 16B stores.
__device__ __forceinline__ void epilogue_transpose_v(
    f32x4 acc[4][4], u16* dst, int m0, int n0, int Hdst, u16* Ts)
{
  const int tid = threadIdx.x, lane = tid & 63, wave = tid >> 6;
  const int wm = (wave >> 1) * 64;
  const int lm = lane & 15, quad = lane >> 4;
  const int bn = m0 >> 11, l0 = m0 & (SEQ - 1);

  #pragma unroll
  for (int pass = 0; pass < 2; ++pass) {
    __syncthreads();   // Ts region free (main-loop / previous-pass reads done)
    if ((wave & 1) == pass) {
      #pragma unroll
      for (int i = 0; i < 4; i++)
        #pragma unroll
        for (int j = 0; j < 4; j++)
          #pragma unroll
          for (int r = 0; r < 4; r++)
            Ts[(j * 16 + lm) * TSTRIDE + wm + i * 16 + quad * 4 + r] =
                f2b(acc[i][j][r]);
    }
    __syncthreads();
    const int hl = (n0 >> 6) + pass;
    u16* base = dst + ((size_t)(bn * Hdst + hl)) * HD * SEQ + l0;
    #pragma unroll
    for (int it = 0; it < 4; ++it) {
      int e = it * 2048 + tid * 8;
      int d = e >> 7, l = e & 127;
      st8(base + (size_t)d * SEQ + l, ld8(Ts + d * TSTRIDE + l));
    }
  }
}

// Merged QKV projection: grid (8, 32, 3), XCD-swizzled, 768 blocks = 3/CU
// (the split qk/v pair ran at 2/CU then 1/CU with a launch gap; LDS is the
// same 32 KB since Ts aliases the dead As/Bs staging buffer).
__global__ __launch_bounds__(256) void gemm_qkv(
    const u16* __restrict__ x,
    const u16* __restrict__ Wq, const u16* __restrict__ Wk, const u16* __restrict__ Wv,
    const float* __restrict__ gq, const float* __restrict__ bq,
    const float* __restrict__ gk, const float* __restrict__ bk,
    u16* __restrict__ qd, u16* __restrict__ kb, u16* __restrict__ vb)
{
  __shared__ __align__(16) u16 buf[128 * 64 * 2];  // As | Bs, reused as Ts
  u16* As = buf;
  u16* Bs = buf + 128 * 64;
  int bx = blockIdx.x, by = blockIdx.y;
  xcd_swz(8, 32, bx, by);
  const int m0 = by * 128, n0 = bx * 128;
  f32x4 acc[4][4];
  if (blockIdx.z == 0) {
    gemm_acc_128x128<0>(x, Wq, m0, n0, As, Bs, acc);
    epilogue_scatter_ln(acc, qd, m0, n0, 0, NHEAD, gq, bq, 1);
  } else if (blockIdx.z == 1) {
    gemm_acc_128x128<0>(x, Wk, m0, n0, As, Bs, acc);
    epilogue_scatter_ln(acc, kb, m0, n0, 0, NHEAD, gk, bk, 1);
  } else {
    gemm_acc_128x128<0>(x, Wv, m0, n0, As, Bs, acc);
    epilogue_transpose_v(acc, vb, m0, n0, NHEAD, buf);
  }
}

// Fallback kernels for small-workspace multi-pass K/V.
__global__ __launch_bounds__(256) void gemm_q(
    const u16* __restrict__ x, const u16* __restrict__ Wq,
    const float* __restrict__ gq, const float* __restrict__ bq,
    u16* __restrict__ qd)
{
  __shared__ __align__(16) u16 As[128 * 64];
  __shared__ __align__(16) u16 Bs[128 * 64];
  int bx = blockIdx.x, by = blockIdx.y;
  xcd_swz(8, 32, bx, by);
  const int m0 = by * 128, n0 = bx * 128;
  f32x4 acc[4][4];
  gemm_acc_128x128<0>(x, Wq, m0, n0, As, Bs, acc);
  epilogue_scatter_ln(acc, qd, m0, n0, 0, NHEAD, gq, bq, 1);
}
__global__ __launch_bounds__(256) void gemm_kv(
    const u16* __restrict__ x,
    const u16* __restrict__ Wk, const u16* __restrict__ Wv,
    const float* __restrict__ gk, const float* __restrict__ bk,
    u16* __restrict__ k, u16* __restrict__ v, int head_lo, int hpp)
{
  __shared__ __align__(16) u16 buf[128 * 64 * 2];
  u16* As = buf;
  u16* Bs = buf + 128 * 64;
  int bx = blockIdx.x, by = blockIdx.y;
  xcd_swz(hpp / 2, 32, bx, by);
  const int m0 = by * 128, n0 = bx * 128;
  const u16* W = (blockIdx.z == 0 ? Wk : Wv) + (size_t)head_lo * HD * EMB;
  f32x4 acc[4][4];
  gemm_acc_128x128<0>(x, W, m0, n0, As, Bs, acc);
  if (blockIdx.z == 0)
    epilogue_scatter_ln(acc, k, m0, n0, 0, hpp, gk, bk, 1);
  else
    epilogue_transpose_v(acc, v, m0, n0, hpp, buf);
}

// ---------------------------------------------------------------------------
// Flash causal attention — REVERTED to the measured-best R6 structure
// (55 us): 256 threads / 4 waves, swapped-QK^T in-register softmax,
// complementary-pair tile map, V^T input, SATT=72 tiles.
// (R7's 128-thread 2-frag variant halved waves/CU -> Occ 26->11%,
// latency-bound regression to 78 us despite fewer LDS ops.)
// ---------------------------------------------------------------------------
__global__ __launch_bounds__(256, 4) void attn(
    u16* qd, const u16* __restrict__ K, const u16* __restrict__ V,
    int head_lo, int hpp)
{
  __shared__ __align__(16) u16 Ks[2][64 * SATT];
  __shared__ __align__(16) u16 Vt[2][64 * SATT];   // V^T: rows=d, cols=key

  const int hl = blockIdx.y, n = blockIdx.z;
  const int perm = (7 * blockIdx.x + (hl & 7) + 8 * n) & 31;
  const int p = perm ^ (31 * (hl >> 3));            // complementary pairs
  const int tid = threadIdx.x, lane = tid & 63, wave = tid >> 6;
  const int lm = lane & 15, quad = lane >> 4, lk = quad * 8;
  u16* Qh = qd + ((size_t)(n * NHEAD + head_lo + hl)) * SEQ * HD;
  const u16* Kh = K + ((size_t)(n * hpp + hl)) * SEQ * HD;
  const u16* Vh = V + ((size_t)(n * hpp + hl)) * HD * SEQ;   // transposed

  const int sr = tid >> 3;        // K: key row 0..31
  const int sc = (tid & 7) * 8;   // K: d col
  const int vd = tid >> 2;        // V^T: d row 0..63
  const int vc = (tid & 3) * 16;  // V^T: key col {0,16,32,48}

  // Q fragment (B-operand of swapped QK^T): rows p*64 + wave*16 + lm
  bf16x8 aq[2];
  #pragma unroll
  for (int ks = 0; ks < 2; ++ks)
    aq[ks] = asbf(ld8(Qh + (size_t)(p * 64 + wave * 16 + lm) * HD + ks * 32 + lk));

  u16x8 kr0, kr1, vr0, vr1;
  kr0 = ld8(Kh + (size_t)(sr)      * HD + sc);
  kr1 = ld8(Kh + (size_t)(sr + 32) * HD + sc);
  vr0 = ld8(Vh + (size_t)vd * SEQ + vc);
  vr1 = ld8(Vh + (size_t)vd * SEQ + vc + 8);
  st8(&Ks[0][sr * SATT + sc], kr0);
  st8(&Ks[0][(sr + 32) * SATT + sc], kr1);
  st8(&Vt[0][vd * SATT + vc], vr0);
  st8(&Vt[0][vd * SATT + vc + 8], vr1);
  kr0 = ld8(Kh + (size_t)(64 + sr)      * HD + sc);
  kr1 = ld8(Kh + (size_t)(64 + sr + 32) * HD + sc);
  vr0 = ld8(Vh + (size_t)vd * SEQ + 64 + vc);
  vr1 = ld8(Vh + (size_t)vd * SEQ + 64 + vc + 8);
  __syncthreads();

  f32x4 oacc[4];
  #pragma unroll
  for (int j = 0; j < 4; j++)
    #pragma unroll
    for (int e = 0; e < 4; e++) oacc[j][e] = 0.f;
  float m_i = -1e30f, psum = 0.f;

  const int idx0 = (((quad & 1) * 2) * 16 + lm) * 4;   // bpermute byte idx, w<2
  const int idx1 = idx0 + 64;                          // w>=2
  const int qrow = p * 64 + wave * 16 + lm;

  for (int t = 0; t <= p; ++t) {
    const int cur = t & 1;
    if (t < p) {
      const int nb = 1 - cur;
      st8(&Ks[nb][sr * SATT + sc], kr0);
      st8(&Ks[nb][(sr + 32) * SATT + sc], kr1);
      st8(&Vt[nb][vd * SATT + vc], vr0);
      st8(&Vt[nb][vd * SATT + vc + 8], vr1);
      if (t + 1 < p) {
        const size_t base = (size_t)(t + 2) * 64;
        kr0 = ld8(Kh + (base + sr)      * HD + sc);
        kr1 = ld8(Kh + (base + sr + 32) * HD + sc);
        vr0 = ld8(Vh + (size_t)vd * SEQ + base + vc);
        vr1 = ld8(Vh + (size_t)vd * SEQ + base + vc + 8);
      }
    }

    // S^T: s[j][r] = S[q=qrow][key = t*64 + j*16 + quad*4 + r]
    f32x4 s[4];
    #pragma unroll
    for (int j = 0; j < 4; j++)
      #pragma unroll
      for (int e = 0; e < 4; e++) s[j][e] = 0.f;
    __builtin_amdgcn_s_setprio(1);
    #pragma unroll
    for (int ks = 0; ks < 2; ++ks)
      #pragma unroll
      for (int j = 0; j < 4; j++) {
        bf16x8 ak = asbf(ld8(&Ks[cur][(j * 16 + lm) * SATT + ks * 32 + lk]));
        s[j] = __builtin_amdgcn_mfma_f32_16x16x32_bf16(ak, aq[ks], s[j], 0, 0, 0);
      }
    __builtin_amdgcn_s_setprio(0);

    if (t == p) {   // causal mask on the diagonal tile
      #pragma unroll
      for (int j = 0; j < 4; j++)
        #pragma unroll
        for (int r = 0; r < 4; r++)
          if (t * 64 + j * 16 + quad * 4 + r > qrow) s[j][r] = -1e30f;
    }

    // row max: 15 local fmax + cross-quad butterfly (2 shfl)
    float mx = fmaxf(fmaxf(s[0][0], s[0][1]), fmaxf(s[0][2], s[0][3]));
    #pragma unroll
    for (int j = 1; j < 4; j++)
      mx = fmaxf(mx, fmaxf(fmaxf(s[j][0], s[j][1]), fmaxf(s[j][2], s[j][3])));
    mx = fmaxf(mx, __shfl_xor(mx, 16, 64));
    mx = fmaxf(mx, __shfl_xor(mx, 32, 64));
    const float mnew = fmaxf(m_i, mx);
    const float alpha = __expf(m_i - mnew);
    m_i = mnew;
    float part = 0.f;
    #pragma unroll
    for (int j = 0; j < 4; j++)
      #pragma unroll
      for (int r = 0; r < 4; r++) {
        float pv = __expf(s[j][r] - mnew);
        s[j][r] = pv;
        part += pv;
      }
    psum = psum * alpha + part;

    // rescale O rows (O rows are quad*4+r; alpha lives at row lm -> gather)
    float ar_[4];
    #pragma unroll
    for (int r = 0; r < 4; r++)
      ar_[r] = __shfl(alpha, (lane & 48) | (quad * 4 + r), 64);
    #pragma unroll
    for (int j = 0; j < 4; j++)
      #pragma unroll
      for (int r = 0; r < 4; r++) oacc[j][r] *= ar_[r];

    // pack P pairs: u[2j]=keys(j*16+quad*4+{0,1}), u[2j+1]={2,3}
    uint32_t u[8];
    #pragma unroll
    for (int j = 0; j < 4; j++) {
      u[2 * j]     = cvtpk(s[j][0], s[j][1]);
      u[2 * j + 1] = cvtpk(s[j][2], s[j][3]);
    }

    __builtin_amdgcn_s_setprio(1);
    #pragma unroll
    for (int ks = 0; ks < 2; ++ks) {
      union { uint32_t w[4]; bf16x8 v; } cv;
      #pragma unroll
      for (int w = 0; w < 4; w++) {
        int lo = __builtin_amdgcn_ds_bpermute(w < 2 ? idx0 : idx1,
                                              (int)u[ks * 4 + (w & 1)]);
        int hi = __builtin_amdgcn_ds_bpermute(w < 2 ? idx0 : idx1,
                                              (int)u[ks * 4 + 2 + (w & 1)]);
        cv.w[w] = (quad < 2) ? (uint32_t)lo : (uint32_t)hi;
      }
      bf16x8 ap = cv.v;   // A-frag: P[q=lm][keys ks*32+quad*8 .. +7]
      #pragma unroll
      for (int j = 0; j < 4; j++) {
        bf16x8 bv = asbf(ld8(&Vt[cur][(j * 16 + lm) * SATT + ks * 32 + lk]));
        oacc[j] = __builtin_amdgcn_mfma_f32_16x16x32_bf16(ap, bv, oacc[j], 0, 0, 0);
      }
    }
    __builtin_amdgcn_s_setprio(0);
    __syncthreads();   // single per-iteration barrier (dbuf swap)
  }

  // epilogue: row sum lives at row lm; gather inv to O rows quad*4+r
  float s_ = psum;
  s_ += __shfl_xor(s_, 16, 64);
  s_ += __shfl_xor(s_, 32, 64);
  const float inv = 1.0f / s_;
  float ir_[4];
  #pragma unroll
  for (int r = 0; r < 4; r++)
    ir_[r] = __shfl(inv, (lane & 48) | (quad * 4 + r), 64);
  #pragma unroll
  for (int r = 0; r < 4; r++) {
    const int row = p * 64 + wave * 16 + quad * 4 + r;
    #pragma unroll
    for (int j = 0; j < 4; j++)
      Qh[(size_t)row * HD + j * 16 + lm] = f2b(oacc[j][r] * ir_[r]);
  }
}

// ---------------------------------------------------------------------------
// Output projection, 64x128 tiles, BK=64 dual-panel: grid (8, 64),
// XCD-swizzled. d_out(f32) = ao @ Wo^T + bo ; ao in [N,16,L,64] bf16.
// ---------------------------------------------------------------------------
__global__ __launch_bounds__(256) void gemm_out(
    const u16* __restrict__ ao, const u16* __restrict__ Wo,
    const float* __restrict__ bo, float* __restrict__ out)
{
  __shared__ __align__(16) u16 As[64 * 64];    // 2 panels of 64x32
  __shared__ __align__(16) u16 Bs[128 * 64];   // 2 panels of 128x32
  int bx = blockIdx.x, by = blockIdx.y;
  xcd_swz(8, 64, bx, by);
  const int m0 = by * 64, n0 = bx * 128;
  const int tid  = threadIdx.x;
  const int lane = tid & 63;
  const int wave = tid >> 6;
  const int wm   = (wave >> 1) * 32;
  const int wn   = (wave & 1) * 64;
  const int ar   = tid >> 2;        // 0..63
  const int ac   = (tid & 3) * 8;
  const int lm   = lane & 15;
  const int lk   = (lane >> 4) * 8;

  f32x4 acc[2][4];
  #pragma unroll
  for (int i = 0; i < 2; i++)
    #pragma unroll
    for (int j = 0; j < 4; j++)
      #pragma unroll
      for (int e = 0; e < 4; e++) acc[i][j][e] = 0.f;

  for (int k0 = 0; k0 < EMB; k0 += 64) {
    size_t aoff[2];
    #pragma unroll
    for (int pnl = 0; pnl < 2; pnl++) {
      int kc = k0 + pnl * 32 + ac, h = kc >> 6, d = kc & 63;
      int r0 = m0 + ar;
      aoff[pnl] = (((size_t)((r0 >> 11) * NHEAD + h)) * SEQ + (r0 & (SEQ-1))) * HD + d;
    }
    __syncthreads();
    #pragma unroll
    for (int pnl = 0; pnl < 2; pnl++) {
      async_cp16(ao + aoff[pnl], As + pnl * 2048 + tid * 8);
      async_cp16(Wo + (size_t)(n0 + ar)      * EMB + k0 + pnl * 32 + ac, Bs + pnl * 4096 + tid * 8);
      async_cp16(Wo + (size_t)(n0 + ar + 64) * EMB + k0 + pnl * 32 + ac, Bs + pnl * 4096 + (tid + 256) * 8);
    }
    __syncthreads();

    #pragma unroll
    for (int pnl = 0; pnl < 2; pnl++) {
      bf16x8 af[2], bfr[4];
      #pragma unroll
      for (int i = 0; i < 2; i++)
        af[i] = asbf(ld8(As + pnl * 2048 + (wm + i * 16 + lm) * 32 + lk));
      #pragma unroll
      for (int j = 0; j < 4; j++)
        bfr[j] = asbf(ld8(Bs + pnl * 4096 + (wn + j * 16 + lm) * 32 + lk));
      #pragma unroll
      for (int i = 0; i < 2; i++)
        #pragma unroll
        for (int j = 0; j < 4; j++)
          acc[i][j] = __builtin_amdgcn_mfma_f32_16x16x32_bf16(af[i], bfr[j], acc[i][j], 0, 0, 0);
    }
  }

  const int quad = lane >> 4;
  #pragma unroll
  for (int j = 0; j < 4; j++) {
    int col = n0 + wn + j * 16 + lm;
    float bias = bo[col];
    #pragma unroll
    for (int i = 0; i < 2; i++)
      #pragma unroll
      for (int r = 0; r < 4; r++) {
        int row = m0 + wm + i * 16 + quad * 4 + r;
        out[(size_t)row * EMB + col] = acc[i][j][r] + bias;
      }
  }
}

extern "C" void kernel_launch(void* const* d_in, const int* in_sizes, int n_in,
                              void* d_out, int out_size, void* d_ws, size_t ws_size,
                              hipStream_t stream)
{
  const float* xf  = (const float*)d_in[0];
  const float* Wqf = (const float*)d_in[2];
  const float* Wkf = (const float*)d_in[3];
  const float* Wvf = (const float*)d_in[4];
  const float* gq  = (const float*)d_in[5];
  const float* bq  = (const float*)d_in[6];
  const float* gk  = (const float*)d_in[7];
  const float* bk  = (const float*)d_in[8];
  const float* Wof = (const float*)d_in[9];
  const float* bo  = (const float*)d_in[10];

  const size_t MB = 1u << 20;
  u16* xb  = (u16*)d_ws;                           // 8 MiB
  u16* wqb = xb  + (size_t)ROWS * EMB;             // 2 MiB each
  u16* wkb = wqb + (size_t)EMB * EMB;
  u16* wvb = wkb + (size_t)EMB * EMB;
  u16* wob = wvb + (size_t)EMB * EMB;
  u16* kvbase = wob + (size_t)EMB * EMB;           // ws + 16 MiB

  size_t avail = (ws_size > 16 * MB) ? ws_size - 16 * MB : 2 * MB;
  int hpp = NHEAD;
  while ((size_t)hpp * MB > avail && hpp > 2) hpp >>= 1;
  const size_t kv_elems = (size_t)hpp * NBATCH * SEQ * HD;
  u16* kbuf = kvbase;
  u16* vbuf = kbuf + kv_elems;

  // Q (bf16, + in-place attn output) lives in the x input buffer (dead
  // after cvt_all). gemm_out writes f32 straight to d_out.
  u16* qd = (u16*)d_in[0];
  float* out = (float*)d_out;

  cvt_all<<<dim3(8192), 256, 0, stream>>>(xf, Wqf, Wkf, Wvf, Wof,
                                          xb, wqb, wkb, wvb, wob);
  if (hpp == NHEAD) {
    gemm_qkv<<<dim3(8, 32, 3), 256, 0, stream>>>(xb, wqb, wkb, wvb,
                                                 gq, bq, gk, bk,
                                                 qd, kbuf, vbuf);
    attn<<<dim3(32, NHEAD, NBATCH), 256, 0, stream>>>(qd, kbuf, vbuf, 0, NHEAD);
  } else {
    gemm_q<<<dim3(8, 32), 256, 0, stream>>>(xb, wqb, gq, bq, qd);
    for (int g = 0; g < NHEAD / hpp; ++g) {
      gemm_kv<<<dim3(hpp / 2, 32, 2), 256, 0, stream>>>(xb, wkb, wvb, gk, bk,
                                                        kbuf, vbuf, g * hpp, hpp);
      attn<<<dim3(32, hpp, NBATCH), 256, 0, stream>>>(qd, kbuf, vbuf, g * hpp, hpp);
    }
  }
  gemm_out<<<dim3(8, 64), 256, 0, stream>>>(qd, wob, bo, out);
}

// Round 9
// 202.670 us; speedup vs baseline: 1.1466x; 1.0963x over previous
//
#include <hip/hip_runtime.h>
#include <stdint.h>

typedef unsigned short u16;
typedef u16   u16x4    __attribute__((ext_vector_type(4)));
typedef u16   u16x8    __attribute__((ext_vector_type(8)));
typedef u16x8 u16x8_ma __attribute__((may_alias));
typedef __bf16 bf16x8  __attribute__((ext_vector_type(8)));
typedef float f32x4    __attribute__((ext_vector_type(4)));
typedef f32x4 f32x4_ma __attribute__((may_alias));

#define EMB    1024
#define NHEAD  16
#define HD     64
#define SEQ    2048
#define NBATCH 2
#define ROWS   (NBATCH*SEQ)   // 4096
#define SATT   72             // attn K/V^T LDS row stride (balanced 8x4-bank groups)
#define TSTRIDE 132           // producer V-transpose LDS stride

__device__ __forceinline__ u16 f2b(float f) {
  uint32_t u; __builtin_memcpy(&u, &f, 4);
  u = u + 0x7fffu + ((u >> 16) & 1u);
  return (u16)(u >> 16);
}
__device__ __forceinline__ u16x8 ld8(const u16* p) { return *(const u16x8_ma*)p; }
__device__ __forceinline__ void  st8(u16* p, u16x8 v) { *(u16x8_ma*)p = v; }
__device__ __forceinline__ bf16x8 asbf(u16x8 v) {
  union { u16x8 u; bf16x8 b; } c; c.u = v; return c.b;
}
// packed f32x2 -> bf16x2 (RNE), T12 recipe (no builtin on gfx950)
__device__ __forceinline__ uint32_t cvtpk(float a, float b) {
  uint32_t r;
  asm("v_cvt_pk_bf16_f32 %0, %1, %2" : "=v"(r) : "v"(a), "v"(b));
  return r;
}
// gfx950 dual-output lane swaps (VALU pipe, replaces ds_bpermute).
// pl32: a' = {a[0:31], b[0:31]}, b' = {a[32:63], b[32:63]}
// pl16: a' = {a.q0, b.q0, a.q2, b.q2}, b' = {a.q1, b.q1, a.q3, b.q3}
__device__ __forceinline__ void pl32swap(uint32_t &a, uint32_t &b) {
  asm("v_permlane32_swap_b32 %0, %1" : "+v"(a), "+v"(b));
}
__device__ __forceinline__ void pl16swap(uint32_t &a, uint32_t &b) {
  asm("v_permlane16_swap_b32 %0, %1" : "+v"(a), "+v"(b));
}
// async global->LDS, 16B/lane; LDS dest = wave-uniform base + lane*16 (m97).
__device__ __forceinline__ void async_cp16(const u16* g, u16* l) {
  __builtin_amdgcn_global_load_lds(
      (const __attribute__((address_space(1))) void*)g,
      (__attribute__((address_space(3))) void*)l, 16, 0, 0);
}
// XCD-chunked bijective block swizzle (T1).
__device__ __forceinline__ void xcd_swz(int gx, int gy, int &bx, int &by) {
  int lin = bx + gx * by;
  int q = (gx * gy) >> 3;
  int w = (lin & 7) * q + (lin >> 3);
  bx = w % gx; by = w / gx;
}

// ---------------------------------------------------------------------------
// Fused f32 -> bf16 conversion: x (4096 blocks) + 4 weights (1024 each).
// ---------------------------------------------------------------------------
__global__ __launch_bounds__(256) void cvt_all(
    const float* __restrict__ x,
    const float* __restrict__ w0, const float* __restrict__ w1,
    const float* __restrict__ w2, const float* __restrict__ w3,
    u16* __restrict__ xd, u16* __restrict__ d0, u16* __restrict__ d1,
    u16* __restrict__ d2, u16* __restrict__ d3)
{
  int bid = blockIdx.x;
  const float* s; u16* d; int off;
  if (bid < 4096) { s = x; d = xd; off = bid; }
  else {
    int t = bid - 4096; int m = t >> 10; off = t & 1023;
    switch (m) {
      case 0: s = w0; d = d0; break;
      case 1: s = w1; d = d1; break;
      case 2: s = w2; d = d2; break;
      default: s = w3; d = d3; break;
    }
  }
  size_t i = ((size_t)off * 256 + threadIdx.x) * 4;
  f32x4 v = *(const f32x4_ma*)(s + i);
  u16x4 o;
  #pragma unroll
  for (int j = 0; j < 4; j++) o[j] = f2b(v[j]);
  *(u16x4*)(d + i) = o;
}

// ---------------------------------------------------------------------------
// 128x128 GEMM core, BK=64 via dual 128x32 panels (m97 layout preserved).
// ---------------------------------------------------------------------------
template<int AMODE>
__device__ __forceinline__ void gemm_acc_128x128(
    const u16* __restrict__ A, const u16* __restrict__ B,
    int m0, int n0, u16* As, u16* Bs, f32x4 acc[4][4])
{
  const int tid  = threadIdx.x;
  const int lane = tid & 63;
  const int wave = tid >> 6;
  const int wm   = (wave >> 1) * 64;
  const int wn   = (wave & 1) * 64;
  const int ar   = tid >> 2;        // 0..63
  const int ac   = (tid & 3) * 8;   // 0,8,16,24
  const int lm   = lane & 15;
  const int lk   = (lane >> 4) * 8;

  #pragma unroll
  for (int i = 0; i < 4; i++)
    #pragma unroll
    for (int j = 0; j < 4; j++)
      #pragma unroll
      for (int e = 0; e < 4; e++) acc[i][j][e] = 0.f;

  for (int k0 = 0; k0 < EMB; k0 += 64) {
    size_t a0[2], a1[2];
    #pragma unroll
    for (int pnl = 0; pnl < 2; pnl++) {
      int kc = k0 + pnl * 32 + ac;
      if (AMODE == 0) {
        a0[pnl] = (size_t)(m0 + ar)      * EMB + kc;
        a1[pnl] = (size_t)(m0 + ar + 64) * EMB + kc;
      } else {
        int h = kc >> 6, d = kc & 63;
        int r0 = m0 + ar, r1 = m0 + ar + 64;
        a0[pnl] = (((size_t)((r0 >> 11) * NHEAD + h)) * SEQ + (r0 & (SEQ-1))) * HD + d;
        a1[pnl] = (((size_t)((r1 >> 11) * NHEAD + h)) * SEQ + (r1 & (SEQ-1))) * HD + d;
      }
    }
    __syncthreads();   // previous iteration's LDS reads complete
    #pragma unroll
    for (int pnl = 0; pnl < 2; pnl++) {
      const int pb = pnl * 4096;   // panel base (elems)
      async_cp16(A + a0[pnl], As + pb + tid * 8);
      async_cp16(A + a1[pnl], As + pb + (tid + 256) * 8);
      async_cp16(B + (size_t)(n0 + ar)      * EMB + k0 + pnl * 32 + ac, Bs + pb + tid * 8);
      async_cp16(B + (size_t)(n0 + ar + 64) * EMB + k0 + pnl * 32 + ac, Bs + pb + (tid + 256) * 8);
    }
    __syncthreads();   // drains vmcnt: both panels ready

    #pragma unroll
    for (int pnl = 0; pnl < 2; pnl++) {
      const int pb = pnl * 4096;
      bf16x8 af[4], bfr[4];
      #pragma unroll
      for (int i = 0; i < 4; i++)
        af[i] = asbf(ld8(As + pb + (wm + i * 16 + lm) * 32 + lk));
      #pragma unroll
      for (int j = 0; j < 4; j++)
        bfr[j] = asbf(ld8(Bs + pb + (wn + j * 16 + lm) * 32 + lk));
      #pragma unroll
      for (int i = 0; i < 4; i++)
        #pragma unroll
        for (int j = 0; j < 4; j++)
          acc[i][j] = __builtin_amdgcn_mfma_f32_16x16x32_bf16(af[i], bfr[j], acc[i][j], 0, 0, 0);
    }
  }
}

// LN over the wave's 64-col head span + scatter to bf16 [N, Hdst, L, 64].
__device__ __forceinline__ void epilogue_scatter_ln(
    f32x4 acc[4][4], u16* dst, int m0, int n0, int head_base, int Hdst,
    const float* g, const float* b, int do_ln)
{
  const int lane = threadIdx.x & 63, wave = threadIdx.x >> 6;
  const int wm = (wave >> 1) * 64, wn = (wave & 1) * 64;
  const int lm = lane & 15, quad = lane >> 4;

  float gv[4], bv[4];
  #pragma unroll
  for (int j = 0; j < 4; j++) { gv[j] = g[j * 16 + lm]; bv[j] = b[j * 16 + lm]; }

  #pragma unroll
  for (int i = 0; i < 4; i++)
    #pragma unroll
    for (int r = 0; r < 4; r++) {
      float val[4];
      #pragma unroll
      for (int j = 0; j < 4; j++) val[j] = acc[i][j][r];
      if (do_ln) {
        float s = val[0] + val[1] + val[2] + val[3];
        #pragma unroll
        for (int o = 8; o >= 1; o >>= 1) s += __shfl_xor(s, o, 64);
        float mean = s * (1.f / 64.f);
        float ss = 0.f;
        #pragma unroll
        for (int j = 0; j < 4; j++) { val[j] -= mean; ss += val[j] * val[j]; }
        #pragma unroll
        for (int o = 8; o >= 1; o >>= 1) ss += __shfl_xor(ss, o, 64);
        float inv = rsqrtf(ss * (1.f / 64.f) + 1e-5f);
        #pragma unroll
        for (int j = 0; j < 4; j++) val[j] = val[j] * inv * gv[j] + bv[j];
      }
      int row = m0 + wm + i * 16 + quad * 4 + r;
      int bn = row >> 11, l = row & (SEQ - 1);
      #pragma unroll
      for (int j = 0; j < 4; j++) {
        int col = n0 + wn + j * 16 + lm;
        int hl = (col >> 6) - head_base, d = col & 63;
        dst[(((size_t)(bn * Hdst + hl)) * SEQ + l) * HD + d] = f2b(val[j]);
      }
    }
}

// V epilogue: transpose the 128x128 tile through LDS (Ts reuses dead As/Bs),
// then write V^T ([N, Hdst, 64, SEQ]) with fully coalesced 16B stores.
__device__ __forceinline__ void epilogue_transpose_v(
    f32x4 acc[4][4], u16* dst, int m0, int n0, int Hdst, u16* Ts)
{
  const int tid = threadIdx.x, lane = tid & 63, wave = tid >> 6;
  const int wm = (wave >> 1) * 64;
  const int lm = lane & 15, quad = lane >> 4;
  const int bn = m0 >> 11, l0 = m0 & (SEQ - 1);

  #pragma unroll
  for (int pass = 0; pass < 2; ++pass) {
    __syncthreads();   // Ts region free (main-loop / previous-pass reads done)
    if ((wave & 1) == pass) {
      #pragma unroll
      for (int i = 0; i < 4; i++)
        #pragma unroll
        for (int j = 0; j < 4; j++)
          #pragma unroll
          for (int r = 0; r < 4; r++)
            Ts[(j * 16 + lm) * TSTRIDE + wm + i * 16 + quad * 4 + r] =
                f2b(acc[i][j][r]);
    }
    __syncthreads();
    const int hl = (n0 >> 6) + pass;
    u16* base = dst + ((size_t)(bn * Hdst + hl)) * HD * SEQ + l0;
    #pragma unroll
    for (int it = 0; it < 4; ++it) {
      int e = it * 2048 + tid * 8;
      int d = e >> 7, l = e & 127;
      st8(base + (size_t)d * SEQ + l, ld8(Ts + d * TSTRIDE + l));
    }
  }
}

// Q/K projection: grid (8, 32, 2), XCD-swizzled. (Split from V: merging all
// three raised VGPR to 132 -> 3 blocks/CU and cost 16 us — R8 post-mortem.)
__global__ __launch_bounds__(256) void gemm_qk(
    const u16* __restrict__ x,
    const u16* __restrict__ Wq, const u16* __restrict__ Wk,
    const float* __restrict__ gq, const float* __restrict__ bq,
    const float* __restrict__ gk, const float* __restrict__ bk,
    u16* __restrict__ qd, u16* __restrict__ kb)
{
  __shared__ __align__(16) u16 As[128 * 64];
  __shared__ __align__(16) u16 Bs[128 * 64];
  int bx = blockIdx.x, by = blockIdx.y;
  xcd_swz(8, 32, bx, by);
  const int m0 = by * 128, n0 = bx * 128;
  f32x4 acc[4][4];
  if (blockIdx.z == 0) {
    gemm_acc_128x128<0>(x, Wq, m0, n0, As, Bs, acc);
    epilogue_scatter_ln(acc, qd, m0, n0, 0, NHEAD, gq, bq, 1);
  } else {
    gemm_acc_128x128<0>(x, Wk, m0, n0, As, Bs, acc);
    epilogue_scatter_ln(acc, kb, m0, n0, 0, NHEAD, gk, bk, 1);
  }
}

// V projection (transposed output): grid (8, 32), XCD-swizzled.
__global__ __launch_bounds__(256) void gemm_v(
    const u16* __restrict__ x, const u16* __restrict__ Wv,
    u16* __restrict__ vb)
{
  __shared__ __align__(16) u16 buf[128 * 64 * 2];  // As | Bs, reused as Ts
  u16* As = buf;
  u16* Bs = buf + 128 * 64;
  int bx = blockIdx.x, by = blockIdx.y;
  xcd_swz(8, 32, bx, by);
  const int m0 = by * 128, n0 = bx * 128;
  f32x4 acc[4][4];
  gemm_acc_128x128<0>(x, Wv, m0, n0, As, Bs, acc);
  epilogue_transpose_v(acc, vb, m0, n0, NHEAD, buf);
}

// Fallback kernels for small-workspace multi-pass K/V.
__global__ __launch_bounds__(256) void gemm_q(
    const u16* __restrict__ x, const u16* __restrict__ Wq,
    const float* __restrict__ gq, const float* __restrict__ bq,
    u16* __restrict__ qd)
{
  __shared__ __align__(16) u16 As[128 * 64];
  __shared__ __align__(16) u16 Bs[128 * 64];
  int bx = blockIdx.x, by = blockIdx.y;
  xcd_swz(8, 32, bx, by);
  const int m0 = by * 128, n0 = bx * 128;
  f32x4 acc[4][4];
  gemm_acc_128x128<0>(x, Wq, m0, n0, As, Bs, acc);
  epilogue_scatter_ln(acc, qd, m0, n0, 0, NHEAD, gq, bq, 1);
}
__global__ __launch_bounds__(256) void gemm_kv(
    const u16* __restrict__ x,
    const u16* __restrict__ Wk, const u16* __restrict__ Wv,
    const float* __restrict__ gk, const float* __restrict__ bk,
    u16* __restrict__ k, u16* __restrict__ v, int head_lo, int hpp)
{
  __shared__ __align__(16) u16 buf[128 * 64 * 2];
  u16* As = buf;
  u16* Bs = buf + 128 * 64;
  int bx = blockIdx.x, by = blockIdx.y;
  xcd_swz(hpp / 2, 32, bx, by);
  const int m0 = by * 128, n0 = bx * 128;
  const u16* W = (blockIdx.z == 0 ? Wk : Wv) + (size_t)head_lo * HD * EMB;
  f32x4 acc[4][4];
  gemm_acc_128x128<0>(x, W, m0, n0, As, Bs, acc);
  if (blockIdx.z == 0)
    epilogue_scatter_ln(acc, k, m0, n0, 0, hpp, gk, bk, 1);
  else
    epilogue_transpose_v(acc, v, m0, n0, hpp, buf);
}

// ---------------------------------------------------------------------------
// Flash causal attention — R6 structure (measured 55 us) with ONE change:
// the P->A-fragment relayout uses permlane32/16_swap (VALU pipe) instead of
// 16 ds_bpermute + 8 cndmask (LDS pipe). Mapping (verified vs bpermute):
//   w0=(u0q0,u0q2,u2q0,u2q2), w1=(u1q0,u1q2,u3q0,u3q2),
//   w2=(u0q1,u0q3,u2q1,u2q3), w3=(u1q1,u1q3,u3q1,u3q3)
//   = pl32swap(u0,u2); pl16swap -> {w0,w2};  pl32swap(u1,u3); pl16swap -> {w1,w3}.
// 256 threads / 4 waves, swapped-QK^T in-register softmax, complementary-pair
// tile map, V^T input, SATT=72 dbuf tiles.
// ---------------------------------------------------------------------------
__global__ __launch_bounds__(256, 4) void attn(
    u16* qd, const u16* __restrict__ K, const u16* __restrict__ V,
    int head_lo, int hpp)
{
  __shared__ __align__(16) u16 Ks[2][64 * SATT];
  __shared__ __align__(16) u16 Vt[2][64 * SATT];   // V^T: rows=d, cols=key

  const int hl = blockIdx.y, n = blockIdx.z;
  const int perm = (7 * blockIdx.x + (hl & 7) + 8 * n) & 31;
  const int p = perm ^ (31 * (hl >> 3));            // complementary pairs
  const int tid = threadIdx.x, lane = tid & 63, wave = tid >> 6;
  const int lm = lane & 15, quad = lane >> 4, lk = quad * 8;
  u16* Qh = qd + ((size_t)(n * NHEAD + head_lo + hl)) * SEQ * HD;
  const u16* Kh = K + ((size_t)(n * hpp + hl)) * SEQ * HD;
  const u16* Vh = V + ((size_t)(n * hpp + hl)) * HD * SEQ;   // transposed

  const int sr = tid >> 3;        // K: key row 0..31
  const int sc = (tid & 7) * 8;   // K: d col
  const int vd = tid >> 2;        // V^T: d row 0..63
  const int vc = (tid & 3) * 16;  // V^T: key col {0,16,32,48}

  // Q fragment (B-operand of swapped QK^T): rows p*64 + wave*16 + lm
  bf16x8 aq[2];
  #pragma unroll
  for (int ks = 0; ks < 2; ++ks)
    aq[ks] = asbf(ld8(Qh + (size_t)(p * 64 + wave * 16 + lm) * HD + ks * 32 + lk));

  u16x8 kr0, kr1, vr0, vr1;
  kr0 = ld8(Kh + (size_t)(sr)      * HD + sc);
  kr1 = ld8(Kh + (size_t)(sr + 32) * HD + sc);
  vr0 = ld8(Vh + (size_t)vd * SEQ + vc);
  vr1 = ld8(Vh + (size_t)vd * SEQ + vc + 8);
  st8(&Ks[0][sr * SATT + sc], kr0);
  st8(&Ks[0][(sr + 32) * SATT + sc], kr1);
  st8(&Vt[0][vd * SATT + vc], vr0);
  st8(&Vt[0][vd * SATT + vc + 8], vr1);
  kr0 = ld8(Kh + (size_t)(64 + sr)      * HD + sc);
  kr1 = ld8(Kh + (size_t)(64 + sr + 32) * HD + sc);
  vr0 = ld8(Vh + (size_t)vd * SEQ + 64 + vc);
  vr1 = ld8(Vh + (size_t)vd * SEQ + 64 + vc + 8);
  __syncthreads();

  f32x4 oacc[4];
  #pragma unroll
  for (int j = 0; j < 4; j++)
    #pragma unroll
    for (int e = 0; e < 4; e++) oacc[j][e] = 0.f;
  float m_i = -1e30f, psum = 0.f;

  const int qrow = p * 64 + wave * 16 + lm;

  for (int t = 0; t <= p; ++t) {
    const int cur = t & 1;
    if (t < p) {
      const int nb = 1 - cur;
      st8(&Ks[nb][sr * SATT + sc], kr0);
      st8(&Ks[nb][(sr + 32) * SATT + sc], kr1);
      st8(&Vt[nb][vd * SATT + vc], vr0);
      st8(&Vt[nb][vd * SATT + vc + 8], vr1);
      if (t + 1 < p) {
        const size_t base = (size_t)(t + 2) * 64;
        kr0 = ld8(Kh + (base + sr)      * HD + sc);
        kr1 = ld8(Kh + (base + sr + 32) * HD + sc);
        vr0 = ld8(Vh + (size_t)vd * SEQ + base + vc);
        vr1 = ld8(Vh + (size_t)vd * SEQ + base + vc + 8);
      }
    }

    // S^T: s[j][r] = S[q=qrow][key = t*64 + j*16 + quad*4 + r]
    f32x4 s[4];
    #pragma unroll
    for (int j = 0; j < 4; j++)
      #pragma unroll
      for (int e = 0; e < 4; e++) s[j][e] = 0.f;
    __builtin_amdgcn_s_setprio(1);
    #pragma unroll
    for (int ks = 0; ks < 2; ++ks)
      #pragma unroll
      for (int j = 0; j < 4; j++) {
        bf16x8 ak = asbf(ld8(&Ks[cur][(j * 16 + lm) * SATT + ks * 32 + lk]));
        s[j] = __builtin_amdgcn_mfma_f32_16x16x32_bf16(ak, aq[ks], s[j], 0, 0, 0);
      }
    __builtin_amdgcn_s_setprio(0);

    if (t == p) {   // causal mask on the diagonal tile
      #pragma unroll
      for (int j = 0; j < 4; j++)
        #pragma unroll
        for (int r = 0; r < 4; r++)
          if (t * 64 + j * 16 + quad * 4 + r > qrow) s[j][r] = -1e30f;
    }

    // row max: 15 local fmax + cross-quad butterfly (2 shfl)
    float mx = fmaxf(fmaxf(s[0][0], s[0][1]), fmaxf(s[0][2], s[0][3]));
    #pragma unroll
    for (int j = 1; j < 4; j++)
      mx = fmaxf(mx, fmaxf(fmaxf(s[j][0], s[j][1]), fmaxf(s[j][2], s[j][3])));
    mx = fmaxf(mx, __shfl_xor(mx, 16, 64));
    mx = fmaxf(mx, __shfl_xor(mx, 32, 64));
    const float mnew = fmaxf(m_i, mx);
    const float alpha = __expf(m_i - mnew);
    m_i = mnew;
    float part = 0.f;
    #pragma unroll
    for (int j = 0; j < 4; j++)
      #pragma unroll
      for (int r = 0; r < 4; r++) {
        float pv = __expf(s[j][r] - mnew);
        s[j][r] = pv;
        part += pv;
      }
    psum = psum * alpha + part;

    // rescale O rows (O rows are quad*4+r; alpha lives at row lm -> gather)
    float ar_[4];
    #pragma unroll
    for (int r = 0; r < 4; r++)
      ar_[r] = __shfl(alpha, (lane & 48) | (quad * 4 + r), 64);
    #pragma unroll
    for (int j = 0; j < 4; j++)
      #pragma unroll
      for (int r = 0; r < 4; r++) oacc[j][r] *= ar_[r];

    // pack P pairs: u[2j]=keys(j*16+quad*4+{0,1}), u[2j+1]={2,3}
    uint32_t u[8];
    #pragma unroll
    for (int j = 0; j < 4; j++) {
      u[2 * j]     = cvtpk(s[j][0], s[j][1]);
      u[2 * j + 1] = cvtpk(s[j][2], s[j][3]);
    }

    __builtin_amdgcn_s_setprio(1);
    #pragma unroll
    for (int ks = 0; ks < 2; ++ks) {
      // P relayout via dual-output permlane swaps (VALU, zero LDS-pipe):
      uint32_t a0 = u[ks * 4 + 0], a1 = u[ks * 4 + 1];
      uint32_t a2 = u[ks * 4 + 2], a3 = u[ks * 4 + 3];
      pl32swap(a0, a2);   // a0={u0.lo,u2.lo}, a2={u0.hi,u2.hi}
      pl16swap(a0, a2);   // a0=w0, a2=w2
      pl32swap(a1, a3);
      pl16swap(a1, a3);   // a1=w1, a3=w3
      union { uint32_t w[4]; bf16x8 v; } cv;
      cv.w[0] = a0; cv.w[1] = a1; cv.w[2] = a2; cv.w[3] = a3;
      bf16x8 ap = cv.v;   // A-frag: P[q=lm][keys ks*32+quad*8 .. +7]
      #pragma unroll
      for (int j = 0; j < 4; j++) {
        bf16x8 bv = asbf(ld8(&Vt[cur][(j * 16 + lm) * SATT + ks * 32 + lk]));
        oacc[j] = __builtin_amdgcn_mfma_f32_16x16x32_bf16(ap, bv, oacc[j], 0, 0, 0);
      }
    }
    __builtin_amdgcn_s_setprio(0);
    __syncthreads();   // single per-iteration barrier (dbuf swap)
  }

  // epilogue: row sum lives at row lm; gather inv to O rows quad*4+r
  float s_ = psum;
  s_ += __shfl_xor(s_, 16, 64);
  s_ += __shfl_xor(s_, 32, 64);
  const float inv = 1.0f / s_;
  float ir_[4];
  #pragma unroll
  for (int r = 0; r < 4; r++)
    ir_[r] = __shfl(inv, (lane & 48) | (quad * 4 + r), 64);
  #pragma unroll
  for (int r = 0; r < 4; r++) {
    const int row = p * 64 + wave * 16 + quad * 4 + r;
    #pragma unroll
    for (int j = 0; j < 4; j++)
      Qh[(size_t)row * HD + j * 16 + lm] = f2b(oacc[j][r] * ir_[r]);
  }
}

// ---------------------------------------------------------------------------
// Output projection, 64x128 tiles, BK=64 dual-panel: grid (8, 64),
// XCD-swizzled. d_out(f32) = ao @ Wo^T + bo ; ao in [N,16,L,64] bf16.
// ---------------------------------------------------------------------------
__global__ __launch_bounds__(256) void gemm_out(
    const u16* __restrict__ ao, const u16* __restrict__ Wo,
    const float* __restrict__ bo, float* __restrict__ out)
{
  __shared__ __align__(16) u16 As[64 * 64];    // 2 panels of 64x32
  __shared__ __align__(16) u16 Bs[128 * 64];   // 2 panels of 128x32
  int bx = blockIdx.x, by = blockIdx.y;
  xcd_swz(8, 64, bx, by);
  const int m0 = by * 64, n0 = bx * 128;
  const int tid  = threadIdx.x;
  const int lane = tid & 63;
  const int wave = tid >> 6;
  const int wm   = (wave >> 1) * 32;
  const int wn   = (wave & 1) * 64;
  const int ar   = tid >> 2;        // 0..63
  const int ac   = (tid & 3) * 8;
  const int lm   = lane & 15;
  const int lk   = (lane >> 4) * 8;

  f32x4 acc[2][4];
  #pragma unroll
  for (int i = 0; i < 2; i++)
    #pragma unroll
    for (int j = 0; j < 4; j++)
      #pragma unroll
      for (int e = 0; e < 4; e++) acc[i][j][e] = 0.f;

  for (int k0 = 0; k0 < EMB; k0 += 64) {
    size_t aoff[2];
    #pragma unroll
    for (int pnl = 0; pnl < 2; pnl++) {
      int kc = k0 + pnl * 32 + ac, h = kc >> 6, d = kc & 63;
      int r0 = m0 + ar;
      aoff[pnl] = (((size_t)((r0 >> 11) * NHEAD + h)) * SEQ + (r0 & (SEQ-1))) * HD + d;
    }
    __syncthreads();
    #pragma unroll
    for (int pnl = 0; pnl < 2; pnl++) {
      async_cp16(ao + aoff[pnl], As + pnl * 2048 + tid * 8);
      async_cp16(Wo + (size_t)(n0 + ar)      * EMB + k0 + pnl * 32 + ac, Bs + pnl * 4096 + tid * 8);
      async_cp16(Wo + (size_t)(n0 + ar + 64) * EMB + k0 + pnl * 32 + ac, Bs + pnl * 4096 + (tid + 256) * 8);
    }
    __syncthreads();

    #pragma unroll
    for (int pnl = 0; pnl < 2; pnl++) {
      bf16x8 af[2], bfr[4];
      #pragma unroll
      for (int i = 0; i < 2; i++)
        af[i] = asbf(ld8(As + pnl * 2048 + (wm + i * 16 + lm) * 32 + lk));
      #pragma unroll
      for (int j = 0; j < 4; j++)
        bfr[j] = asbf(ld8(Bs + pnl * 4096 + (wn + j * 16 + lm) * 32 + lk));
      #pragma unroll
      for (int i = 0; i < 2; i++)
        #pragma unroll
        for (int j = 0; j < 4; j++)
          acc[i][j] = __builtin_amdgcn_mfma_f32_16x16x32_bf16(af[i], bfr[j], acc[i][j], 0, 0, 0);
    }
  }

  const int quad = lane >> 4;
  #pragma unroll
  for (int j = 0; j < 4; j++) {
    int col = n0 + wn + j * 16 + lm;
    float bias = bo[col];
    #pragma unroll
    for (int i = 0; i < 2; i++)
      #pragma unroll
      for (int r = 0; r < 4; r++) {
        int row = m0 + wm + i * 16 + quad * 4 + r;
        out[(size_t)row * EMB + col] = acc[i][j][r] + bias;
      }
  }
}

extern "C" void kernel_launch(void* const* d_in, const int* in_sizes, int n_in,
                              void* d_out, int out_size, void* d_ws, size_t ws_size,
                              hipStream_t stream)
{
  const float* xf  = (const float*)d_in[0];
  const float* Wqf = (const float*)d_in[2];
  const float* Wkf = (const float*)d_in[3];
  const float* Wvf = (const float*)d_in[4];
  const float* gq  = (const float*)d_in[5];
  const float* bq  = (const float*)d_in[6];
  const float* gk  = (const float*)d_in[7];
  const float* bk  = (const float*)d_in[8];
  const float* Wof = (const float*)d_in[9];
  const float* bo  = (const float*)d_in[10];

  const size_t MB = 1u << 20;
  u16* xb  = (u16*)d_ws;                           // 8 MiB
  u16* wqb = xb  + (size_t)ROWS * EMB;             // 2 MiB each
  u16* wkb = wqb + (size_t)EMB * EMB;
  u16* wvb = wkb + (size_t)EMB * EMB;
  u16* wob = wvb + (size_t)EMB * EMB;
  u16* kvbase = wob + (size_t)EMB * EMB;           // ws + 16 MiB

  size_t avail = (ws_size > 16 * MB) ? ws_size - 16 * MB : 2 * MB;
  int hpp = NHEAD;
  while ((size_t)hpp * MB > avail && hpp > 2) hpp >>= 1;
  const size_t kv_elems = (size_t)hpp * NBATCH * SEQ * HD;
  u16* kbuf = kvbase;
  u16* vbuf = kbuf + kv_elems;

  // Q (bf16, + in-place attn output) lives in the x input buffer (dead
  // after cvt_all). gemm_out writes f32 straight to d_out.
  u16* qd = (u16*)d_in[0];
  float* out = (float*)d_out;

  cvt_all<<<dim3(8192), 256, 0, stream>>>(xf, Wqf, Wkf, Wvf, Wof,
                                          xb, wqb, wkb, wvb, wob);
  if (hpp == NHEAD) {
    gemm_qk<<<dim3(8, 32, 2), 256, 0, stream>>>(xb, wqb, wkb,
                                                gq, bq, gk, bk, qd, kbuf);
    gemm_v<<<dim3(8, 32), 256, 0, stream>>>(xb, wvb, vbuf);
    attn<<<dim3(32, NHEAD, NBATCH), 256, 0, stream>>>(qd, kbuf, vbuf, 0, NHEAD);
  } else {
    gemm_q<<<dim3(8, 32), 256, 0, stream>>>(xb, wqb, gq, bq, qd);
    for (int g = 0; g < NHEAD / hpp; ++g) {
      gemm_kv<<<dim3(hpp / 2, 32, 2), 256, 0, stream>>>(xb, wkb, wvb, gk, bk,
                                                        kbuf, vbuf, g * hpp, hpp);
      attn<<<dim3(32, hpp, NBATCH), 256, 0, stream>>>(qd, kbuf, vbuf, g * hpp, hpp);
    }
  }
  gemm_out<<<dim3(8, 64), 256, 0, stream>>>(qd, wob, bo, out);
}

// Round 10
// 198.937 us; speedup vs baseline: 1.1681x; 1.0188x over previous
//
#include <hip/hip_runtime.h>
#include <stdint.h>

typedef unsigned short u16;
typedef u16   u16x4    __attribute__((ext_vector_type(4)));
typedef u16   u16x8    __attribute__((ext_vector_type(8)));
typedef u16x8 u16x8_ma __attribute__((may_alias));
typedef __bf16 bf16x8  __attribute__((ext_vector_type(8)));
typedef float f32x4    __attribute__((ext_vector_type(4)));
typedef f32x4 f32x4_ma __attribute__((may_alias));

#define EMB    1024
#define NHEAD  16
#define HD     64
#define SEQ    2048
#define NBATCH 2
#define ROWS   (NBATCH*SEQ)   // 4096
#define SATT   72             // attn K/V^T LDS row stride (balanced 8x4-bank groups)
#define TSTRIDE 132           // producer V-transpose LDS stride

__device__ __forceinline__ u16 f2b(float f) {
  uint32_t u; __builtin_memcpy(&u, &f, 4);
  u = u + 0x7fffu + ((u >> 16) & 1u);
  return (u16)(u >> 16);
}
__device__ __forceinline__ u16x8 ld8(const u16* p) { return *(const u16x8_ma*)p; }
__device__ __forceinline__ void  st8(u16* p, u16x8 v) { *(u16x8_ma*)p = v; }
__device__ __forceinline__ bf16x8 asbf(u16x8 v) {
  union { u16x8 u; bf16x8 b; } c; c.u = v; return c.b;
}
// packed f32x2 -> bf16x2 (RNE), T12 recipe (no builtin on gfx950)
__device__ __forceinline__ uint32_t cvtpk(float a, float b) {
  uint32_t r;
  asm("v_cvt_pk_bf16_f32 %0, %1, %2" : "=v"(r) : "v"(a), "v"(b));
  return r;
}
// gfx950 dual-output lane swaps (VALU pipe, replaces ds_bpermute).
__device__ __forceinline__ void pl32swap(uint32_t &a, uint32_t &b) {
  asm("v_permlane32_swap_b32 %0, %1" : "+v"(a), "+v"(b));
}
__device__ __forceinline__ void pl16swap(uint32_t &a, uint32_t &b) {
  asm("v_permlane16_swap_b32 %0, %1" : "+v"(a), "+v"(b));
}
// async global->LDS, 16B/lane; LDS dest = wave-uniform base + lane*16 (m97).
__device__ __forceinline__ void async_cp16(const u16* g, u16* l) {
  __builtin_amdgcn_global_load_lds(
      (const __attribute__((address_space(1))) void*)g,
      (__attribute__((address_space(3))) void*)l, 16, 0, 0);
}
// XCD-chunked bijective block swizzle (T1).
__device__ __forceinline__ void xcd_swz(int gx, int gy, int &bx, int &by) {
  int lin = bx + gx * by;
  int q = (gx * gy) >> 3;
  int w = (lin & 7) * q + (lin >> 3);
  bx = w % gx; by = w / gx;
}

// ---------------------------------------------------------------------------
// Fused f32 -> bf16 conversion: x (4096 blocks) + 4 weights (1024 each).
// ---------------------------------------------------------------------------
__global__ __launch_bounds__(256) void cvt_all(
    const float* __restrict__ x,
    const float* __restrict__ w0, const float* __restrict__ w1,
    const float* __restrict__ w2, const float* __restrict__ w3,
    u16* __restrict__ xd, u16* __restrict__ d0, u16* __restrict__ d1,
    u16* __restrict__ d2, u16* __restrict__ d3)
{
  int bid = blockIdx.x;
  const float* s; u16* d; int off;
  if (bid < 4096) { s = x; d = xd; off = bid; }
  else {
    int t = bid - 4096; int m = t >> 10; off = t & 1023;
    switch (m) {
      case 0: s = w0; d = d0; break;
      case 1: s = w1; d = d1; break;
      case 2: s = w2; d = d2; break;
      default: s = w3; d = d3; break;
    }
  }
  size_t i = ((size_t)off * 256 + threadIdx.x) * 4;
  f32x4 v = *(const f32x4_ma*)(s + i);
  u16x4 o;
  #pragma unroll
  for (int j = 0; j < 4; j++) o[j] = f2b(v[j]);
  *(u16x4*)(d + i) = o;
}

// ---------------------------------------------------------------------------
// 128x128 GEMM core, BK=64 via dual 128x32 panels (m97 layout preserved).
// ---------------------------------------------------------------------------
template<int AMODE>
__device__ __forceinline__ void gemm_acc_128x128(
    const u16* __restrict__ A, const u16* __restrict__ B,
    int m0, int n0, u16* As, u16* Bs, f32x4 acc[4][4])
{
  const int tid  = threadIdx.x;
  const int lane = tid & 63;
  const int wave = tid >> 6;
  const int wm   = (wave >> 1) * 64;
  const int wn   = (wave & 1) * 64;
  const int ar   = tid >> 2;        // 0..63
  const int ac   = (tid & 3) * 8;   // 0,8,16,24
  const int lm   = lane & 15;
  const int lk   = (lane >> 4) * 8;

  #pragma unroll
  for (int i = 0; i < 4; i++)
    #pragma unroll
    for (int j = 0; j < 4; j++)
      #pragma unroll
      for (int e = 0; e < 4; e++) acc[i][j][e] = 0.f;

  for (int k0 = 0; k0 < EMB; k0 += 64) {
    size_t a0[2], a1[2];
    #pragma unroll
    for (int pnl = 0; pnl < 2; pnl++) {
      int kc = k0 + pnl * 32 + ac;
      if (AMODE == 0) {
        a0[pnl] = (size_t)(m0 + ar)      * EMB + kc;
        a1[pnl] = (size_t)(m0 + ar + 64) * EMB + kc;
      } else {
        int h = kc >> 6, d = kc & 63;
        int r0 = m0 + ar, r1 = m0 + ar + 64;
        a0[pnl] = (((size_t)((r0 >> 11) * NHEAD + h)) * SEQ + (r0 & (SEQ-1))) * HD + d;
        a1[pnl] = (((size_t)((r1 >> 11) * NHEAD + h)) * SEQ + (r1 & (SEQ-1))) * HD + d;
      }
    }
    __syncthreads();   // previous iteration's LDS reads complete
    #pragma unroll
    for (int pnl = 0; pnl < 2; pnl++) {
      const int pb = pnl * 4096;   // panel base (elems)
      async_cp16(A + a0[pnl], As + pb + tid * 8);
      async_cp16(A + a1[pnl], As + pb + (tid + 256) * 8);
      async_cp16(B + (size_t)(n0 + ar)      * EMB + k0 + pnl * 32 + ac, Bs + pb + tid * 8);
      async_cp16(B + (size_t)(n0 + ar + 64) * EMB + k0 + pnl * 32 + ac, Bs + pb + (tid + 256) * 8);
    }
    __syncthreads();   // drains vmcnt: both panels ready

    #pragma unroll
    for (int pnl = 0; pnl < 2; pnl++) {
      const int pb = pnl * 4096;
      bf16x8 af[4], bfr[4];
      #pragma unroll
      for (int i = 0; i < 4; i++)
        af[i] = asbf(ld8(As + pb + (wm + i * 16 + lm) * 32 + lk));
      #pragma unroll
      for (int j = 0; j < 4; j++)
        bfr[j] = asbf(ld8(Bs + pb + (wn + j * 16 + lm) * 32 + lk));
      #pragma unroll
      for (int i = 0; i < 4; i++)
        #pragma unroll
        for (int j = 0; j < 4; j++)
          acc[i][j] = __builtin_amdgcn_mfma_f32_16x16x32_bf16(af[i], bfr[j], acc[i][j], 0, 0, 0);
    }
  }
}

// LN over the wave's 64-col head span + scatter to bf16 [N, Hdst, L, 64].
__device__ __forceinline__ void epilogue_scatter_ln(
    f32x4 acc[4][4], u16* dst, int m0, int n0, int head_base, int Hdst,
    const float* g, const float* b, int do_ln)
{
  const int lane = threadIdx.x & 63, wave = threadIdx.x >> 6;
  const int wm = (wave >> 1) * 64, wn = (wave & 1) * 64;
  const int lm = lane & 15, quad = lane >> 4;

  float gv[4], bv[4];
  #pragma unroll
  for (int j = 0; j < 4; j++) { gv[j] = g[j * 16 + lm]; bv[j] = b[j * 16 + lm]; }

  #pragma unroll
  for (int i = 0; i < 4; i++)
    #pragma unroll
    for (int r = 0; r < 4; r++) {
      float val[4];
      #pragma unroll
      for (int j = 0; j < 4; j++) val[j] = acc[i][j][r];
      if (do_ln) {
        float s = val[0] + val[1] + val[2] + val[3];
        #pragma unroll
        for (int o = 8; o >= 1; o >>= 1) s += __shfl_xor(s, o, 64);
        float mean = s * (1.f / 64.f);
        float ss = 0.f;
        #pragma unroll
        for (int j = 0; j < 4; j++) { val[j] -= mean; ss += val[j] * val[j]; }
        #pragma unroll
        for (int o = 8; o >= 1; o >>= 1) ss += __shfl_xor(ss, o, 64);
        float inv = rsqrtf(ss * (1.f / 64.f) + 1e-5f);
        #pragma unroll
        for (int j = 0; j < 4; j++) val[j] = val[j] * inv * gv[j] + bv[j];
      }
      int row = m0 + wm + i * 16 + quad * 4 + r;
      int bn = row >> 11, l = row & (SEQ - 1);
      #pragma unroll
      for (int j = 0; j < 4; j++) {
        int col = n0 + wn + j * 16 + lm;
        int hl = (col >> 6) - head_base, d = col & 63;
        dst[(((size_t)(bn * Hdst + hl)) * SEQ + l) * HD + d] = f2b(val[j]);
      }
    }
}

// V epilogue: transpose the 128x128 tile through LDS (Ts reuses dead As/Bs),
// then write V^T ([N, Hdst, 64, SEQ]) with fully coalesced 16B stores.
__device__ __forceinline__ void epilogue_transpose_v(
    f32x4 acc[4][4], u16* dst, int m0, int n0, int Hdst, u16* Ts)
{
  const int tid = threadIdx.x, lane = tid & 63, wave = tid >> 6;
  const int wm = (wave >> 1) * 64;
  const int lm = lane & 15, quad = lane >> 4;
  const int bn = m0 >> 11, l0 = m0 & (SEQ - 1);

  #pragma unroll
  for (int pass = 0; pass < 2; ++pass) {
    __syncthreads();   // Ts region free (main-loop / previous-pass reads done)
    if ((wave & 1) == pass) {
      #pragma unroll
      for (int i = 0; i < 4; i++)
        #pragma unroll
        for (int j = 0; j < 4; j++)
          #pragma unroll
          for (int r = 0; r < 4; r++)
            Ts[(j * 16 + lm) * TSTRIDE + wm + i * 16 + quad * 4 + r] =
                f2b(acc[i][j][r]);
    }
    __syncthreads();
    const int hl = (n0 >> 6) + pass;
    u16* base = dst + ((size_t)(bn * Hdst + hl)) * HD * SEQ + l0;
    #pragma unroll
    for (int it = 0; it < 4; ++it) {
      int e = it * 2048 + tid * 8;
      int d = e >> 7, l = e & 127;
      st8(base + (size_t)d * SEQ + l, ld8(Ts + d * TSTRIDE + l));
    }
  }
}

// Q/K projection: grid (8, 32, 2), XCD-swizzled. (Split from V: merging all
// three raised VGPR to 132 -> 3 blocks/CU and cost 16 us — R8 post-mortem.)
__global__ __launch_bounds__(256) void gemm_qk(
    const u16* __restrict__ x,
    const u16* __restrict__ Wq, const u16* __restrict__ Wk,
    const float* __restrict__ gq, const float* __restrict__ bq,
    const float* __restrict__ gk, const float* __restrict__ bk,
    u16* __restrict__ qd, u16* __restrict__ kb)
{
  __shared__ __align__(16) u16 As[128 * 64];
  __shared__ __align__(16) u16 Bs[128 * 64];
  int bx = blockIdx.x, by = blockIdx.y;
  xcd_swz(8, 32, bx, by);
  const int m0 = by * 128, n0 = bx * 128;
  f32x4 acc[4][4];
  if (blockIdx.z == 0) {
    gemm_acc_128x128<0>(x, Wq, m0, n0, As, Bs, acc);
    epilogue_scatter_ln(acc, qd, m0, n0, 0, NHEAD, gq, bq, 1);
  } else {
    gemm_acc_128x128<0>(x, Wk, m0, n0, As, Bs, acc);
    epilogue_scatter_ln(acc, kb, m0, n0, 0, NHEAD, gk, bk, 1);
  }
}

// V projection (transposed output): grid (8, 32), XCD-swizzled.
__global__ __launch_bounds__(256) void gemm_v(
    const u16* __restrict__ x, const u16* __restrict__ Wv,
    u16* __restrict__ vb)
{
  __shared__ __align__(16) u16 buf[128 * 64 * 2];  // As | Bs, reused as Ts
  u16* As = buf;
  u16* Bs = buf + 128 * 64;
  int bx = blockIdx.x, by = blockIdx.y;
  xcd_swz(8, 32, bx, by);
  const int m0 = by * 128, n0 = bx * 128;
  f32x4 acc[4][4];
  gemm_acc_128x128<0>(x, Wv, m0, n0, As, Bs, acc);
  epilogue_transpose_v(acc, vb, m0, n0, NHEAD, buf);
}

// Fallback kernels for small-workspace multi-pass K/V.
__global__ __launch_bounds__(256) void gemm_q(
    const u16* __restrict__ x, const u16* __restrict__ Wq,
    const float* __restrict__ gq, const float* __restrict__ bq,
    u16* __restrict__ qd)
{
  __shared__ __align__(16) u16 As[128 * 64];
  __shared__ __align__(16) u16 Bs[128 * 64];
  int bx = blockIdx.x, by = blockIdx.y;
  xcd_swz(8, 32, bx, by);
  const int m0 = by * 128, n0 = bx * 128;
  f32x4 acc[4][4];
  gemm_acc_128x128<0>(x, Wq, m0, n0, As, Bs, acc);
  epilogue_scatter_ln(acc, qd, m0, n0, 0, NHEAD, gq, bq, 1);
}
__global__ __launch_bounds__(256) void gemm_kv(
    const u16* __restrict__ x,
    const u16* __restrict__ Wk, const u16* __restrict__ Wv,
    const float* __restrict__ gk, const float* __restrict__ bk,
    u16* __restrict__ k, u16* __restrict__ v, int head_lo, int hpp)
{
  __shared__ __align__(16) u16 buf[128 * 64 * 2];
  u16* As = buf;
  u16* Bs = buf + 128 * 64;
  int bx = blockIdx.x, by = blockIdx.y;
  xcd_swz(hpp / 2, 32, bx, by);
  const int m0 = by * 128, n0 = bx * 128;
  const u16* W = (blockIdx.z == 0 ? Wk : Wv) + (size_t)head_lo * HD * EMB;
  f32x4 acc[4][4];
  gemm_acc_128x128<0>(x, W, m0, n0, As, Bs, acc);
  if (blockIdx.z == 0)
    epilogue_scatter_ln(acc, k, m0, n0, 0, hpp, gk, bk, 1);
  else
    epilogue_transpose_v(acc, v, m0, n0, hpp, buf);
}

// ---------------------------------------------------------------------------
// Flash causal attention — R9 structure (46.8 us) + two orthogonal tweaks:
// 1) XCD head colocation: lin&7 selects the XCD-owned head group, so each
//    XCD's L2 fetches only its 4 heads' K/V (was: every head scattered over
//    all 8 XCDs -> up to 8x K/V overfetch, FETCH 63 MB). Under the +256
//    co-residency pattern a CU's 4 blocks share ONE head with p-quadruple
//    {x, 15-x, 16+x, 31-x} (sum 66 — balanced, bijective per head).
// 2) T13 defer-max: when __all(mx <= m_i + 8) keep the old max — skips the
//    alpha exp, 4 gather shuffles and 16-mul O-rescale (exact math; P
//    bounded by e^8, f32 accumulators).
// ---------------------------------------------------------------------------
__global__ __launch_bounds__(256, 4) void attn(
    u16* qd, const u16* __restrict__ K, const u16* __restrict__ V,
    int head_lo, int hpp)
{
  __shared__ __align__(16) u16 Ks[2][64 * SATT];
  __shared__ __align__(16) u16 Vt[2][64 * SATT];   // V^T: rows=d, cols=key

  int p, hl, n;
  if (hpp == NHEAD) {
    // XCD-colocated map (32 heads = 8 XCD x 4, grid (32,16,2))
    const int lin = blockIdx.x + 32 * (blockIdx.y + NHEAD * blockIdx.z);
    const int xcd = lin & 7, idx = lin >> 3;
    const int slot = idx & 3, pp = idx >> 2;      // pp in 0..31
    const int hi = pp >> 3, lo = pp & 7;
    p = (hi & 1) ? (hi * 8 + 7 - lo) : (hi * 8 + lo);
    const int head = xcd * 4 + slot;
    n = head >> 4; hl = head & 15;
  } else {
    hl = blockIdx.y; n = blockIdx.z;
    const int perm = (7 * blockIdx.x + (hl & 7) + 8 * n) & 31;
    p = perm ^ (31 * (hl >> 3));
  }
  const int tid = threadIdx.x, lane = tid & 63, wave = tid >> 6;
  const int lm = lane & 15, quad = lane >> 4, lk = quad * 8;
  u16* Qh = qd + ((size_t)(n * NHEAD + head_lo + hl)) * SEQ * HD;
  const u16* Kh = K + ((size_t)(n * hpp + hl)) * SEQ * HD;
  const u16* Vh = V + ((size_t)(n * hpp + hl)) * HD * SEQ;   // transposed

  const int sr = tid >> 3;        // K: key row 0..31
  const int sc = (tid & 7) * 8;   // K: d col
  const int vd = tid >> 2;        // V^T: d row 0..63
  const int vc = (tid & 3) * 16;  // V^T: key col {0,16,32,48}

  // Q fragment (B-operand of swapped QK^T): rows p*64 + wave*16 + lm
  bf16x8 aq[2];
  #pragma unroll
  for (int ks = 0; ks < 2; ++ks)
    aq[ks] = asbf(ld8(Qh + (size_t)(p * 64 + wave * 16 + lm) * HD + ks * 32 + lk));

  u16x8 kr0, kr1, vr0, vr1;
  kr0 = ld8(Kh + (size_t)(sr)      * HD + sc);
  kr1 = ld8(Kh + (size_t)(sr + 32) * HD + sc);
  vr0 = ld8(Vh + (size_t)vd * SEQ + vc);
  vr1 = ld8(Vh + (size_t)vd * SEQ + vc + 8);
  st8(&Ks[0][sr * SATT + sc], kr0);
  st8(&Ks[0][(sr + 32) * SATT + sc], kr1);
  st8(&Vt[0][vd * SATT + vc], vr0);
  st8(&Vt[0][vd * SATT + vc + 8], vr1);
  kr0 = ld8(Kh + (size_t)(64 + sr)      * HD + sc);
  kr1 = ld8(Kh + (size_t)(64 + sr + 32) * HD + sc);
  vr0 = ld8(Vh + (size_t)vd * SEQ + 64 + vc);
  vr1 = ld8(Vh + (size_t)vd * SEQ + 64 + vc + 8);
  __syncthreads();

  f32x4 oacc[4];
  #pragma unroll
  for (int j = 0; j < 4; j++)
    #pragma unroll
    for (int e = 0; e < 4; e++) oacc[j][e] = 0.f;
  float m_i = -1e30f, psum = 0.f;

  const int qrow = p * 64 + wave * 16 + lm;

  for (int t = 0; t <= p; ++t) {
    const int cur = t & 1;
    if (t < p) {
      const int nb = 1 - cur;
      st8(&Ks[nb][sr * SATT + sc], kr0);
      st8(&Ks[nb][(sr + 32) * SATT + sc], kr1);
      st8(&Vt[nb][vd * SATT + vc], vr0);
      st8(&Vt[nb][vd * SATT + vc + 8], vr1);
      if (t + 1 < p) {
        const size_t base = (size_t)(t + 2) * 64;
        kr0 = ld8(Kh + (base + sr)      * HD + sc);
        kr1 = ld8(Kh + (base + sr + 32) * HD + sc);
        vr0 = ld8(Vh + (size_t)vd * SEQ + base + vc);
        vr1 = ld8(Vh + (size_t)vd * SEQ + base + vc + 8);
      }
    }

    // S^T: s[j][r] = S[q=qrow][key = t*64 + j*16 + quad*4 + r]
    f32x4 s[4];
    #pragma unroll
    for (int j = 0; j < 4; j++)
      #pragma unroll
      for (int e = 0; e < 4; e++) s[j][e] = 0.f;
    __builtin_amdgcn_s_setprio(1);
    #pragma unroll
    for (int ks = 0; ks < 2; ++ks)
      #pragma unroll
      for (int j = 0; j < 4; j++) {
        bf16x8 ak = asbf(ld8(&Ks[cur][(j * 16 + lm) * SATT + ks * 32 + lk]));
        s[j] = __builtin_amdgcn_mfma_f32_16x16x32_bf16(ak, aq[ks], s[j], 0, 0, 0);
      }
    __builtin_amdgcn_s_setprio(0);

    if (t == p) {   // causal mask on the diagonal tile
      #pragma unroll
      for (int j = 0; j < 4; j++)
        #pragma unroll
        for (int r = 0; r < 4; r++)
          if (t * 64 + j * 16 + quad * 4 + r > qrow) s[j][r] = -1e30f;
    }

    // row max: 15 local fmax + cross-quad butterfly (2 shfl)
    float mx = fmaxf(fmaxf(s[0][0], s[0][1]), fmaxf(s[0][2], s[0][3]));
    #pragma unroll
    for (int j = 1; j < 4; j++)
      mx = fmaxf(mx, fmaxf(fmaxf(s[j][0], s[j][1]), fmaxf(s[j][2], s[j][3])));
    mx = fmaxf(mx, __shfl_xor(mx, 16, 64));
    mx = fmaxf(mx, __shfl_xor(mx, 32, 64));

    // T13 defer-max: skip rescale while the running max still dominates.
    const bool defer = __all(mx <= m_i + 8.f);
    float alpha = 1.f;
    if (!defer) {
      const float mnew = fmaxf(m_i, mx);
      alpha = __expf(m_i - mnew);
      m_i = mnew;
    }
    float part = 0.f;
    #pragma unroll
    for (int j = 0; j < 4; j++)
      #pragma unroll
      for (int r = 0; r < 4; r++) {
        float pv = __expf(s[j][r] - m_i);
        s[j][r] = pv;
        part += pv;
      }
    if (defer) {
      psum += part;
    } else {
      psum = psum * alpha + part;
      // rescale O rows (O rows are quad*4+r; alpha lives at row lm -> gather)
      float ar_[4];
      #pragma unroll
      for (int r = 0; r < 4; r++)
        ar_[r] = __shfl(alpha, (lane & 48) | (quad * 4 + r), 64);
      #pragma unroll
      for (int j = 0; j < 4; j++)
        #pragma unroll
        for (int r = 0; r < 4; r++) oacc[j][r] *= ar_[r];
    }

    // pack P pairs: u[2j]=keys(j*16+quad*4+{0,1}), u[2j+1]={2,3}
    uint32_t u[8];
    #pragma unroll
    for (int j = 0; j < 4; j++) {
      u[2 * j]     = cvtpk(s[j][0], s[j][1]);
      u[2 * j + 1] = cvtpk(s[j][2], s[j][3]);
    }

    __builtin_amdgcn_s_setprio(1);
    #pragma unroll
    for (int ks = 0; ks < 2; ++ks) {
      // P relayout via dual-output permlane swaps (VALU, zero LDS-pipe):
      uint32_t a0 = u[ks * 4 + 0], a1 = u[ks * 4 + 1];
      uint32_t a2 = u[ks * 4 + 2], a3 = u[ks * 4 + 3];
      pl32swap(a0, a2);   // a0={u0.lo,u2.lo}, a2={u0.hi,u2.hi}
      pl16swap(a0, a2);   // a0=w0, a2=w2
      pl32swap(a1, a3);
      pl16swap(a1, a3);   // a1=w1, a3=w3
      union { uint32_t w[4]; bf16x8 v; } cv;
      cv.w[0] = a0; cv.w[1] = a1; cv.w[2] = a2; cv.w[3] = a3;
      bf16x8 ap = cv.v;   // A-frag: P[q=lm][keys ks*32+quad*8 .. +7]
      #pragma unroll
      for (int j = 0; j < 4; j++) {
        bf16x8 bv = asbf(ld8(&Vt[cur][(j * 16 + lm) * SATT + ks * 32 + lk]));
        oacc[j] = __builtin_amdgcn_mfma_f32_16x16x32_bf16(ap, bv, oacc[j], 0, 0, 0);
      }
    }
    __builtin_amdgcn_s_setprio(0);
    __syncthreads();   // single per-iteration barrier (dbuf swap)
  }

  // epilogue: row sum lives at row lm; gather inv to O rows quad*4+r
  float s_ = psum;
  s_ += __shfl_xor(s_, 16, 64);
  s_ += __shfl_xor(s_, 32, 64);
  const float inv = 1.0f / s_;
  float ir_[4];
  #pragma unroll
  for (int r = 0; r < 4; r++)
    ir_[r] = __shfl(inv, (lane & 48) | (quad * 4 + r), 64);
  #pragma unroll
  for (int r = 0; r < 4; r++) {
    const int row = p * 64 + wave * 16 + quad * 4 + r;
    #pragma unroll
    for (int j = 0; j < 4; j++)
      Qh[(size_t)row * HD + j * 16 + lm] = f2b(oacc[j][r] * ir_[r]);
  }
}

// ---------------------------------------------------------------------------
// Output projection, 64x128 tiles, BK=64 dual-panel: grid (8, 64),
// XCD-swizzled. d_out(f32) = ao @ Wo^T + bo ; ao in [N,16,L,64] bf16.
// ---------------------------------------------------------------------------
__global__ __launch_bounds__(256) void gemm_out(
    const u16* __restrict__ ao, const u16* __restrict__ Wo,
    const float* __restrict__ bo, float* __restrict__ out)
{
  __shared__ __align__(16) u16 As[64 * 64];    // 2 panels of 64x32
  __shared__ __align__(16) u16 Bs[128 * 64];   // 2 panels of 128x32
  int bx = blockIdx.x, by = blockIdx.y;
  xcd_swz(8, 64, bx, by);
  const int m0 = by * 64, n0 = bx * 128;
  const int tid  = threadIdx.x;
  const int lane = tid & 63;
  const int wave = tid >> 6;
  const int wm   = (wave >> 1) * 32;
  const int wn   = (wave & 1) * 64;
  const int ar   = tid >> 2;        // 0..63
  const int ac   = (tid & 3) * 8;
  const int lm   = lane & 15;
  const int lk   = (lane >> 4) * 8;

  f32x4 acc[2][4];
  #pragma unroll
  for (int i = 0; i < 2; i++)
    #pragma unroll
    for (int j = 0; j < 4; j++)
      #pragma unroll
      for (int e = 0; e < 4; e++) acc[i][j][e] = 0.f;

  for (int k0 = 0; k0 < EMB; k0 += 64) {
    size_t aoff[2];
    #pragma unroll
    for (int pnl = 0; pnl < 2; pnl++) {
      int kc = k0 + pnl * 32 + ac, h = kc >> 6, d = kc & 63;
      int r0 = m0 + ar;
      aoff[pnl] = (((size_t)((r0 >> 11) * NHEAD + h)) * SEQ + (r0 & (SEQ-1))) * HD + d;
    }
    __syncthreads();
    #pragma unroll
    for (int pnl = 0; pnl < 2; pnl++) {
      async_cp16(ao + aoff[pnl], As + pnl * 2048 + tid * 8);
      async_cp16(Wo + (size_t)(n0 + ar)      * EMB + k0 + pnl * 32 + ac, Bs + pnl * 4096 + tid * 8);
      async_cp16(Wo + (size_t)(n0 + ar + 64) * EMB + k0 + pnl * 32 + ac, Bs + pnl * 4096 + (tid + 256) * 8);
    }
    __syncthreads();

    #pragma unroll
    for (int pnl = 0; pnl < 2; pnl++) {
      bf16x8 af[2], bfr[4];
      #pragma unroll
      for (int i = 0; i < 2; i++)
        af[i] = asbf(ld8(As + pnl * 2048 + (wm + i * 16 + lm) * 32 + lk));
      #pragma unroll
      for (int j = 0; j < 4; j++)
        bfr[j] = asbf(ld8(Bs + pnl * 4096 + (wn + j * 16 + lm) * 32 + lk));
      #pragma unroll
      for (int i = 0; i < 2; i++)
        #pragma unroll
        for (int j = 0; j < 4; j++)
          acc[i][j] = __builtin_amdgcn_mfma_f32_16x16x32_bf16(af[i], bfr[j], acc[i][j], 0, 0, 0);
    }
  }

  const int quad = lane >> 4;
  #pragma unroll
  for (int j = 0; j < 4; j++) {
    int col = n0 + wn + j * 16 + lm;
    float bias = bo[col];
    #pragma unroll
    for (int i = 0; i < 2; i++)
      #pragma unroll
      for (int r = 0; r < 4; r++) {
        int row = m0 + wm + i * 16 + quad * 4 + r;
        out[(size_t)row * EMB + col] = acc[i][j][r] + bias;
      }
  }
}

extern "C" void kernel_launch(void* const* d_in, const int* in_sizes, int n_in,
                              void* d_out, int out_size, void* d_ws, size_t ws_size,
                              hipStream_t stream)
{
  const float* xf  = (const float*)d_in[0];
  const float* Wqf = (const float*)d_in[2];
  const float* Wkf = (const float*)d_in[3];
  const float* Wvf = (const float*)d_in[4];
  const float* gq  = (const float*)d_in[5];
  const float* bq  = (const float*)d_in[6];
  const float* gk  = (const float*)d_in[7];
  const float* bk  = (const float*)d_in[8];
  const float* Wof = (const float*)d_in[9];
  const float* bo  = (const float*)d_in[10];

  const size_t MB = 1u << 20;
  u16* xb  = (u16*)d_ws;                           // 8 MiB
  u16* wqb = xb  + (size_t)ROWS * EMB;             // 2 MiB each
  u16* wkb = wqb + (size_t)EMB * EMB;
  u16* wvb = wkb + (size_t)EMB * EMB;
  u16* wob = wvb + (size_t)EMB * EMB;
  u16* kvbase = wob + (size_t)EMB * EMB;           // ws + 16 MiB

  size_t avail = (ws_size > 16 * MB) ? ws_size - 16 * MB : 2 * MB;
  int hpp = NHEAD;
  while ((size_t)hpp * MB > avail && hpp > 2) hpp >>= 1;
  const size_t kv_elems = (size_t)hpp * NBATCH * SEQ * HD;
  u16* kbuf = kvbase;
  u16* vbuf = kbuf + kv_elems;

  // Q (bf16, + in-place attn output) lives in the x input buffer (dead
  // after cvt_all). gemm_out writes f32 straight to d_out.
  u16* qd = (u16*)d_in[0];
  float* out = (float*)d_out;

  cvt_all<<<dim3(8192), 256, 0, stream>>>(xf, Wqf, Wkf, Wvf, Wof,
                                          xb, wqb, wkb, wvb, wob);
  if (hpp == NHEAD) {
    gemm_qk<<<dim3(8, 32, 2), 256, 0, stream>>>(xb, wqb, wkb,
                                                gq, bq, gk, bk, qd, kbuf);
    gemm_v<<<dim3(8, 32), 256, 0, stream>>>(xb, wvb, vbuf);
    attn<<<dim3(32, NHEAD, NBATCH), 256, 0, stream>>>(qd, kbuf, vbuf, 0, NHEAD);
  } else {
    gemm_q<<<dim3(8, 32), 256, 0, stream>>>(xb, wqb, gq, bq, qd);
    for (int g = 0; g < NHEAD / hpp; ++g) {
      gemm_kv<<<dim3(hpp / 2, 32, 2), 256, 0, stream>>>(xb, wkb, wvb, gk, bk,
                                                        kbuf, vbuf, g * hpp, hpp);
      attn<<<dim3(32, hpp, NBATCH), 256, 0, stream>>>(qd, kbuf, vbuf, g * hpp, hpp);
    }
  }
  gemm_out<<<dim3(8, 64), 256, 0, stream>>>(qd, wob, bo, out);
}